// Round 1
// baseline (1356.538 us; speedup 1.0000x reference)
//
#include <hip/hip_runtime.h>

#define LRELU(v) ((v) > 0.0f ? (v) : 0.01f * (v))

// ---------------- histogram of col (in-degree for both SAGE and edge convs) --
__global__ void hist_k(const int* __restrict__ col, int* __restrict__ cnt, int E) {
    int e = blockIdx.x * blockDim.x + threadIdx.x;
    if (e < E) atomicAdd(&cnt[col[e]], 1);
}

// ---------------- SAGE: scatter-add h[row[e]] into acc[col[e]] ---------------
template <int F>
__global__ void sage_scatter_k(const float* __restrict__ h, const int* __restrict__ row,
                               const int* __restrict__ col, float* __restrict__ acc, int E) {
    int t = blockIdx.x * blockDim.x + threadIdx.x;
    if (t >= E * F) return;
    int e = t / F;
    int f = t % F;
    atomicAdd(&acc[col[e] * F + f], h[row[e] * F + f]);
}

// ---------------- SAGE: out = leaky(mean@wl + bl + h@wr) --------------------
template <int FIN, int FOUT>
__global__ void sage_compute_k(const float* __restrict__ acc, const int* __restrict__ cnt,
                               const float* __restrict__ h, const float* __restrict__ wl,
                               const float* __restrict__ bl, const float* __restrict__ wr,
                               float* __restrict__ out, int N) {
    constexpr int NPB = 256 / FOUT;
    __shared__ float swl[FIN * FOUT];
    __shared__ float swr[FIN * FOUT];
    int lin = threadIdx.y * FOUT + threadIdx.x;
    for (int idx = lin; idx < FIN * FOUT; idx += 256) {
        swl[idx] = wl[idx];
        swr[idx] = wr[idx];
    }
    __syncthreads();
    int i = blockIdx.x * NPB + threadIdx.y;
    if (i >= N) return;
    int o = threadIdx.x;
    float inv = 1.0f / fmaxf((float)cnt[i], 1.0f);
    float s = bl[o];
    for (int f = 0; f < FIN; ++f) {
        s += acc[i * FIN + f] * inv * swl[f * FOUT + o] + h[i * FIN + f] * swr[f * FOUT + o];
    }
    out[i * FOUT + o] = LRELU(s);
}

// ---------------- edge conv layer 0: scatter raw dis (8-wide) over all E ----
__global__ void scatter_dis_k(const float* __restrict__ dis, const int* __restrict__ col,
                              float* __restrict__ acc, int E) {
    int t = blockIdx.x * blockDim.x + threadIdx.x;
    if (t >= E * 8) return;
    int e = t >> 3;
    int f = t & 7;
    atomicAdd(&acc[col[e] * 8 + f], dis[t]);
}

// ---------------- edge conv layers 1-3: scatter delta = dv[e]-c over e<N ----
template <int H>
__global__ void edge_scatter_k(const float* __restrict__ dv, const float* __restrict__ cvec,
                               const int* __restrict__ col, float* __restrict__ sd, int Ne) {
    int t = blockIdx.x * blockDim.x + threadIdx.x;
    if (t >= Ne * H) return;
    int e = t / H;
    int f = t % H;
    atomicAdd(&sd[col[e] * H + f], dv[t] - cvec[f]);
}

// ---------------- edge conv compute for rows t<N ----------------------------
// aggr[k] = (deg*m[k] + dot(sd[t], w1[:,k]) + b1[k]) / (deg+1)
// out[o]  = leaky(dot(aggr, w2[:,o]) + b2[o])
// Layer 0 is the same formula with m = b1 and sd = scattered dis sums.
template <int HIN, int H2, int HOUT>
__global__ void edge_compute_k(const float* __restrict__ sd, const int* __restrict__ cnt,
                               const float* __restrict__ m, const float* __restrict__ w1,
                               const float* __restrict__ b1, const float* __restrict__ w2,
                               const float* __restrict__ b2, float* __restrict__ out, int N) {
    __shared__ float aggr[H2];
    __shared__ float ssd[HIN];
    int t = blockIdx.x;
    int tid = threadIdx.x;  // H2 threads
    float deg = (float)cnt[t];
    float inv = 1.0f / (deg + 1.0f);
    for (int f = tid; f < HIN; f += H2) ssd[f] = sd[t * HIN + f];
    __syncthreads();
    float s = deg * m[tid] + b1[tid];
    for (int f = 0; f < HIN; ++f) s += ssd[f] * w1[f * H2 + tid];
    aggr[tid] = s * inv;
    __syncthreads();
    if (tid < HOUT) {
        float o = b2[tid];
        for (int k = 0; k < H2; ++k) o += aggr[k] * w2[k * HOUT + tid];
        out[t * HOUT + tid] = LRELU(o);
    }
}

// ---------------- constants: c_{l+1} = leaky(b1_l@w2_l + b2_l), m_l = c_l@w1_l + b1_l
__global__ void consts_k(const float* __restrict__ e0_b1, const float* __restrict__ e0_w2,
                         const float* __restrict__ e0_b2, const float* __restrict__ e1_w1,
                         const float* __restrict__ e1_b1, const float* __restrict__ e1_w2,
                         const float* __restrict__ e1_b2, const float* __restrict__ e2_w1,
                         const float* __restrict__ e2_b1, const float* __restrict__ e2_w2,
                         const float* __restrict__ e2_b2, const float* __restrict__ e3_w1,
                         const float* __restrict__ e3_b1, const float* __restrict__ e3_w2,
                         const float* __restrict__ e3_b2, float* __restrict__ cbuf) {
    __shared__ float c1[64], c2[64], c3[32], c4[32];
    int tid = threadIdx.x;  // 128 threads
    if (tid < 64) {
        float s = e0_b2[tid];
        for (int k = 0; k < 128; ++k) s += e0_b1[k] * e0_w2[k * 64 + tid];
        c1[tid] = LRELU(s);
    }
    if (tid < 64) {
        float s = e1_b2[tid];
        for (int k = 0; k < 128; ++k) s += e1_b1[k] * e1_w2[k * 64 + tid];
        c2[tid] = LRELU(s);
    }
    if (tid < 32) {
        float s = e2_b2[tid];
        for (int k = 0; k < 64; ++k) s += e2_b1[k] * e2_w2[k * 32 + tid];
        c3[tid] = LRELU(s);
    }
    if (tid < 32) {
        float s = e3_b2[tid];
        for (int k = 0; k < 64; ++k) s += e3_b1[k] * e3_w2[k * 32 + tid];
        c4[tid] = LRELU(s);
    }
    __syncthreads();
    // write c's
    if (tid < 64) cbuf[tid] = c1[tid];
    if (tid < 64) cbuf[64 + tid] = c2[tid];
    if (tid < 32) cbuf[128 + tid] = c3[tid];
    if (tid < 32) cbuf[160 + tid] = c4[tid];
    // m1 [128]
    {
        float s = e1_b1[tid];
        for (int f = 0; f < 64; ++f) s += c1[f] * e1_w1[f * 128 + tid];
        cbuf[192 + tid] = s;
    }
    // m2 [64]
    if (tid < 64) {
        float s = e2_b1[tid];
        for (int f = 0; f < 64; ++f) s += c2[f] * e2_w1[f * 64 + tid];
        cbuf[320 + tid] = s;
    }
    // m3 [64]
    if (tid < 64) {
        float s = e3_b1[tid];
        for (int f = 0; f < 32; ++f) s += c3[f] * e3_w1[f * 64 + tid];
        cbuf[384 + tid] = s;
    }
}

// ---------------- final: out[e] = dot(h[row]*h[col], fcw[0:32]) + dot(d[e], fcw[32:64]) + fcb
__global__ void final_k(const float* __restrict__ h3, const float* __restrict__ dv3,
                        const float* __restrict__ c4, const int* __restrict__ row,
                        const int* __restrict__ col, const float* __restrict__ fcw,
                        const float* __restrict__ fcb, float* __restrict__ out, int E, int N) {
    __shared__ float sw[64];
    __shared__ float sc4[32];
    int tid = threadIdx.x;
    if (tid < 64) sw[tid] = fcw[tid];
    if (tid < 32) sc4[tid] = c4[tid];
    __syncthreads();
    int e = blockIdx.x * blockDim.x + tid;
    if (e >= E) return;
    int r = row[e], c = col[e];
    const float4* hr = (const float4*)(h3 + (size_t)r * 32);
    const float4* hc = (const float4*)(h3 + (size_t)c * 32);
    float s = fcb[0];
#pragma unroll
    for (int q = 0; q < 8; ++q) {
        float4 a = hr[q], b = hc[q];
        s += a.x * b.x * sw[q * 4 + 0] + a.y * b.y * sw[q * 4 + 1] + a.z * b.z * sw[q * 4 + 2] +
             a.w * b.w * sw[q * 4 + 3];
    }
    if (e < N) {
        const float4* dp = (const float4*)(dv3 + (size_t)e * 32);
#pragma unroll
        for (int q = 0; q < 8; ++q) {
            float4 d = dp[q];
            s += d.x * sw[32 + q * 4 + 0] + d.y * sw[32 + q * 4 + 1] + d.z * sw[32 + q * 4 + 2] +
                 d.w * sw[32 + q * 4 + 3];
        }
    } else {
#pragma unroll
        for (int k = 0; k < 32; ++k) s += sc4[k] * sw[32 + k];
    }
    out[e] = s;
}

extern "C" void kernel_launch(void* const* d_in, const int* in_sizes, int n_in, void* d_out,
                              int out_size, void* d_ws, size_t ws_size, hipStream_t stream) {
    const float* x = (const float*)d_in[0];
    const float* dis = (const float*)d_in[1];
    const int* ei = (const int*)d_in[2];
    const float* s_wl[4] = {(const float*)d_in[3], (const float*)d_in[6], (const float*)d_in[9],
                            (const float*)d_in[12]};
    const float* s_bl[4] = {(const float*)d_in[4], (const float*)d_in[7], (const float*)d_in[10],
                            (const float*)d_in[13]};
    const float* s_wr[4] = {(const float*)d_in[5], (const float*)d_in[8], (const float*)d_in[11],
                            (const float*)d_in[14]};
    const float* e_w1[4] = {(const float*)d_in[15], (const float*)d_in[19], (const float*)d_in[23],
                            (const float*)d_in[27]};
    const float* e_b1[4] = {(const float*)d_in[16], (const float*)d_in[20], (const float*)d_in[24],
                            (const float*)d_in[28]};
    const float* e_w2[4] = {(const float*)d_in[17], (const float*)d_in[21], (const float*)d_in[25],
                            (const float*)d_in[29]};
    const float* e_b2[4] = {(const float*)d_in[18], (const float*)d_in[22], (const float*)d_in[26],
                            (const float*)d_in[30]};
    const float* fcw = (const float*)d_in[31];
    const float* fcb = (const float*)d_in[32];

    const int N = in_sizes[0] / 64;
    const int E = in_sizes[1] / 8;
    const int* row = ei;
    const int* col = ei + E;

    char* ws = (char*)d_ws;
    int* cnt = (int*)ws;
    ws += (size_t)N * 4;
    float* acc = (float*)ws;
    ws += (size_t)N * 64 * 4;
    float* hA = (float*)ws;
    ws += (size_t)N * 64 * 4;
    float* hB = (float*)ws;
    ws += (size_t)N * 64 * 4;
    float* dvA = (float*)ws;
    ws += (size_t)N * 64 * 4;
    float* dvB = (float*)ws;
    ws += (size_t)N * 64 * 4;
    float* cbuf = (float*)ws;

    // ---- degree histogram (shared by SAGE mean and edge-conv denominators)
    hipMemsetAsync(cnt, 0, (size_t)N * 4, stream);
    hist_k<<<(E + 255) / 256, 256, 0, stream>>>(col, cnt, E);

    // ---- SAGE layer 0: x -> hA (64->64)
    hipMemsetAsync(acc, 0, (size_t)N * 64 * 4, stream);
    sage_scatter_k<64><<<(E * 64 + 255) / 256, 256, 0, stream>>>(x, row, col, acc, E);
    sage_compute_k<64, 64><<<(N + 3) / 4, dim3(64, 4), 0, stream>>>(acc, cnt, x, s_wl[0], s_bl[0],
                                                                    s_wr[0], hA, N);
    // ---- SAGE layer 1: hA -> hB (64->64)
    hipMemsetAsync(acc, 0, (size_t)N * 64 * 4, stream);
    sage_scatter_k<64><<<(E * 64 + 255) / 256, 256, 0, stream>>>(hA, row, col, acc, E);
    sage_compute_k<64, 64><<<(N + 3) / 4, dim3(64, 4), 0, stream>>>(acc, cnt, hA, s_wl[1], s_bl[1],
                                                                    s_wr[1], hB, N);
    // ---- SAGE layer 2: hB -> hA (64->32)
    hipMemsetAsync(acc, 0, (size_t)N * 64 * 4, stream);
    sage_scatter_k<64><<<(E * 64 + 255) / 256, 256, 0, stream>>>(hB, row, col, acc, E);
    sage_compute_k<64, 32><<<(N + 7) / 8, dim3(32, 8), 0, stream>>>(acc, cnt, hB, s_wl[2], s_bl[2],
                                                                    s_wr[2], hA, N);
    // ---- SAGE layer 3: hA -> hB (32->32)
    hipMemsetAsync(acc, 0, (size_t)N * 32 * 4, stream);
    sage_scatter_k<32><<<(E * 32 + 255) / 256, 256, 0, stream>>>(hA, row, col, acc, E);
    sage_compute_k<32, 32><<<(N + 7) / 8, dim3(32, 8), 0, stream>>>(acc, cnt, hA, s_wl[3], s_bl[3],
                                                                    s_wr[3], hB, N);

    // ---- constants for edge-conv decomposition
    consts_k<<<1, 128, 0, stream>>>(e_b1[0], e_w2[0], e_b2[0], e_w1[1], e_b1[1], e_w2[1], e_b2[1],
                                    e_w1[2], e_b1[2], e_w2[2], e_b2[2], e_w1[3], e_b1[3], e_w2[3],
                                    e_b2[3], cbuf);

    // ---- edge conv layer 0: dis -> dvA (varying rows t<N only; rows>=N are c1)
    hipMemsetAsync(acc, 0, (size_t)N * 8 * 4, stream);
    scatter_dis_k<<<(E * 8 + 255) / 256, 256, 0, stream>>>(dis, col, acc, E);
    edge_compute_k<8, 128, 64><<<N, 128, 0, stream>>>(acc, cnt, e_b1[0], e_w1[0], e_b1[0], e_w2[0],
                                                      e_b2[0], dvA, N);
    // ---- edge conv layer 1: dvA (+c1) -> dvB
    hipMemsetAsync(acc, 0, (size_t)N * 64 * 4, stream);
    edge_scatter_k<64><<<(N * 64 + 255) / 256, 256, 0, stream>>>(dvA, cbuf + 0, col, acc, N);
    edge_compute_k<64, 128, 64><<<N, 128, 0, stream>>>(acc, cnt, cbuf + 192, e_w1[1], e_b1[1],
                                                       e_w2[1], e_b2[1], dvB, N);
    // ---- edge conv layer 2: dvB (+c2) -> dvA (width 32 out)
    hipMemsetAsync(acc, 0, (size_t)N * 64 * 4, stream);
    edge_scatter_k<64><<<(N * 64 + 255) / 256, 256, 0, stream>>>(dvB, cbuf + 64, col, acc, N);
    edge_compute_k<64, 64, 32><<<N, 64, 0, stream>>>(acc, cnt, cbuf + 320, e_w1[2], e_b1[2],
                                                     e_w2[2], e_b2[2], dvA, N);
    // ---- edge conv layer 3: dvA (+c3) -> dvB (width 32 out)
    hipMemsetAsync(acc, 0, (size_t)N * 32 * 4, stream);
    edge_scatter_k<32><<<(N * 32 + 255) / 256, 256, 0, stream>>>(dvA, cbuf + 128, col, acc, N);
    edge_compute_k<32, 64, 32><<<N, 64, 0, stream>>>(acc, cnt, cbuf + 384, e_w1[3], e_b1[3],
                                                     e_w2[3], e_b2[3], dvB, N);

    // ---- final per-edge output
    final_k<<<(E + 255) / 256, 256, 0, stream>>>(hB, dvB, cbuf + 160, row, col, fcw, fcb,
                                                 (float*)d_out, E, N);
}

// Round 2
// 1124.395 us; speedup vs baseline: 1.2065x; 1.2065x over previous
//
#include <hip/hip_runtime.h>

#define LRELU(v) ((v) > 0.0f ? (v) : 0.01f * (v))

// ---------------- histogram of col (in-degree) -------------------------------
__global__ void hist_k(const int* __restrict__ col, int* __restrict__ cnt, int E) {
    int e = blockIdx.x * blockDim.x + threadIdx.x;
    if (e < E) atomicAdd(&cnt[col[e]], 1);
}

// ---------------- single-block exclusive scan of cnt -> rowptr, wp ----------
__global__ void scan_k(const int* __restrict__ cnt, int* __restrict__ rowptr,
                       int* __restrict__ wp, int N) {
    __shared__ int sums[1024];
    int tid = threadIdx.x;
    int chunk = (N + 1023) / 1024;
    int start = tid * chunk;
    int end = min(start + chunk, N);
    int local = 0;
    for (int i = start; i < end; ++i) local += cnt[i];
    sums[tid] = local;
    __syncthreads();
    // inclusive Hillis-Steele scan over 1024 partials
    for (int off = 1; off < 1024; off <<= 1) {
        int v = (tid >= off) ? sums[tid - off] : 0;
        __syncthreads();
        sums[tid] += v;
        __syncthreads();
    }
    int run = (tid == 0) ? 0 : sums[tid - 1];
    for (int i = start; i < end; ++i) {
        rowptr[i] = run;
        wp[i] = run;
        run += cnt[i];
    }
    if (tid == 1023) rowptr[N] = sums[1023];
}

// ---------------- CSR build: place (row[e], e) into slot for col[e] ----------
__global__ void csr_build_k(const int* __restrict__ row, const int* __restrict__ col,
                            int* __restrict__ wp, int* __restrict__ ssrc,
                            int* __restrict__ seid, int E) {
    int e = blockIdx.x * blockDim.x + threadIdx.x;
    if (e >= E) return;
    int pos = atomicAdd(&wp[col[e]], 1);
    ssrc[pos] = row[e];
    seid[pos] = e;
}

// ---------------- SAGE aggregate (gather), 64-wide: one wave per node --------
__global__ void sage_aggr64_k(const float* __restrict__ h, const int* __restrict__ rowptr,
                              const int* __restrict__ ssrc, float* __restrict__ acc, int N) {
    int wave = (blockIdx.x * blockDim.x + threadIdx.x) >> 6;
    int lane = threadIdx.x & 63;
    if (wave >= N) return;
    int s = rowptr[wave], e = rowptr[wave + 1];
    float a = 0.0f;
    int p = s;
    for (; p + 1 < e; p += 2) {
        int s0 = ssrc[p], s1 = ssrc[p + 1];
        a += h[(size_t)s0 * 64 + lane] + h[(size_t)s1 * 64 + lane];
    }
    if (p < e) a += h[(size_t)ssrc[p] * 64 + lane];
    acc[(size_t)wave * 64 + lane] = a;
}

// ---------------- SAGE aggregate, 32-wide: wave handles 2 neighbors at once --
__global__ void sage_aggr32_k(const float* __restrict__ h, const int* __restrict__ rowptr,
                              const int* __restrict__ ssrc, float* __restrict__ acc, int N) {
    int wave = (blockIdx.x * blockDim.x + threadIdx.x) >> 6;
    int lane = threadIdx.x & 63;
    if (wave >= N) return;
    int f = lane & 31, u = lane >> 5;
    int s = rowptr[wave], e = rowptr[wave + 1];
    float a = 0.0f;
    for (int p = s + u; p < e; p += 2) a += h[(size_t)ssrc[p] * 32 + f];
    a += __shfl_down(a, 32);
    if (u == 0) acc[(size_t)wave * 32 + f] = a;
}

// ---------------- SAGE: out = leaky(mean@wl + bl + h@wr) ---------------------
template <int FIN, int FOUT>
__global__ void sage_compute_k(const float* __restrict__ acc, const int* __restrict__ cnt,
                               const float* __restrict__ h, const float* __restrict__ wl,
                               const float* __restrict__ bl, const float* __restrict__ wr,
                               float* __restrict__ out, int N) {
    constexpr int NPB = 256 / FOUT;
    __shared__ float swl[FIN * FOUT];
    __shared__ float swr[FIN * FOUT];
    int lin = threadIdx.y * FOUT + threadIdx.x;
    for (int idx = lin; idx < FIN * FOUT; idx += 256) {
        swl[idx] = wl[idx];
        swr[idx] = wr[idx];
    }
    __syncthreads();
    int i = blockIdx.x * NPB + threadIdx.y;
    if (i >= N) return;
    int o = threadIdx.x;
    float inv = 1.0f / fmaxf((float)cnt[i], 1.0f);
    float s = bl[o];
    for (int f = 0; f < FIN; ++f) {
        s += acc[i * FIN + f] * inv * swl[f * FOUT + o] + h[i * FIN + f] * swr[f * FOUT + o];
    }
    out[i * FOUT + o] = LRELU(s);
}

// ---------------- edge conv layer 0 aggregate: sum dis[eid] (8-wide) ---------
__global__ void edge_aggr8_k(const float* __restrict__ dis, const int* __restrict__ rowptr,
                             const int* __restrict__ seid, float* __restrict__ sd, int N) {
    int wave = (blockIdx.x * blockDim.x + threadIdx.x) >> 6;
    int lane = threadIdx.x & 63;
    if (wave >= N) return;
    int f = lane & 7, u = lane >> 3;  // 8 neighbors in parallel
    int s = rowptr[wave], e = rowptr[wave + 1];
    float a = 0.0f;
    for (int p = s + u; p < e; p += 8) a += dis[(size_t)seid[p] * 8 + f];
    a += __shfl_down(a, 32);
    a += __shfl_down(a, 16);
    a += __shfl_down(a, 8);
    if (lane < 8) sd[(size_t)wave * 8 + lane] = a;
}

// ---------------- edge conv layers 1-3 aggregate: sum (dv[eid]-c), eid<N -----
__global__ void edge_aggr_delta64_k(const float* __restrict__ dv, const float* __restrict__ cvec,
                                    const int* __restrict__ rowptr, const int* __restrict__ seid,
                                    float* __restrict__ sd, int N) {
    int wave = (blockIdx.x * blockDim.x + threadIdx.x) >> 6;
    int lane = threadIdx.x & 63;
    if (wave >= N) return;
    float c = cvec[lane];
    int s = rowptr[wave], e = rowptr[wave + 1];
    float a = 0.0f;
    for (int p = s; p < e; ++p) {
        int eid = seid[p];
        if (eid < N) a += dv[(size_t)eid * 64 + lane] - c;
    }
    sd[(size_t)wave * 64 + lane] = a;
}

__global__ void edge_aggr_delta32_k(const float* __restrict__ dv, const float* __restrict__ cvec,
                                    const int* __restrict__ rowptr, const int* __restrict__ seid,
                                    float* __restrict__ sd, int N) {
    int wave = (blockIdx.x * blockDim.x + threadIdx.x) >> 6;
    int lane = threadIdx.x & 63;
    if (wave >= N) return;
    int f = lane & 31, u = lane >> 5;
    float c = cvec[f];
    int s = rowptr[wave], e = rowptr[wave + 1];
    float a = 0.0f;
    for (int p = s + u; p < e; p += 2) {
        int eid = seid[p];
        if (eid < N) a += dv[(size_t)eid * 32 + f] - c;
    }
    a += __shfl_down(a, 32);
    if (u == 0) sd[(size_t)wave * 32 + f] = a;
}

// ---------------- edge conv compute for rows t<N -----------------------------
// aggr[k] = (deg*m[k] + dot(sd[t], w1[:,k]) + b1[k]) / (deg+1)
// out[o]  = leaky(dot(aggr, w2[:,o]) + b2[o])
template <int HIN, int H2, int HOUT>
__global__ void edge_compute_k(const float* __restrict__ sd, const int* __restrict__ cnt,
                               const float* __restrict__ m, const float* __restrict__ w1,
                               const float* __restrict__ b1, const float* __restrict__ w2,
                               const float* __restrict__ b2, float* __restrict__ out, int N) {
    __shared__ float aggr[H2];
    __shared__ float ssd[HIN];
    int t = blockIdx.x;
    int tid = threadIdx.x;  // H2 threads
    float deg = (float)cnt[t];
    float inv = 1.0f / (deg + 1.0f);
    for (int f = tid; f < HIN; f += H2) ssd[f] = sd[t * HIN + f];
    __syncthreads();
    float s = deg * m[tid] + b1[tid];
    for (int f = 0; f < HIN; ++f) s += ssd[f] * w1[f * H2 + tid];
    aggr[tid] = s * inv;
    __syncthreads();
    if (tid < HOUT) {
        float o = b2[tid];
        for (int k = 0; k < H2; ++k) o += aggr[k] * w2[k * HOUT + tid];
        out[t * HOUT + tid] = LRELU(o);
    }
}

// ---------------- constants: c_{l+1} = leaky(b1_l@w2_l + b2_l), m_l = c_l@w1_l + b1_l
__global__ void consts_k(const float* __restrict__ e0_b1, const float* __restrict__ e0_w2,
                         const float* __restrict__ e0_b2, const float* __restrict__ e1_w1,
                         const float* __restrict__ e1_b1, const float* __restrict__ e1_w2,
                         const float* __restrict__ e1_b2, const float* __restrict__ e2_w1,
                         const float* __restrict__ e2_b1, const float* __restrict__ e2_w2,
                         const float* __restrict__ e2_b2, const float* __restrict__ e3_w1,
                         const float* __restrict__ e3_b1, const float* __restrict__ e3_w2,
                         const float* __restrict__ e3_b2, float* __restrict__ cbuf) {
    __shared__ float c1[64], c2[64], c3[32], c4[32];
    int tid = threadIdx.x;  // 128 threads
    if (tid < 64) {
        float s = e0_b2[tid];
        for (int k = 0; k < 128; ++k) s += e0_b1[k] * e0_w2[k * 64 + tid];
        c1[tid] = LRELU(s);
    }
    if (tid < 64) {
        float s = e1_b2[tid];
        for (int k = 0; k < 128; ++k) s += e1_b1[k] * e1_w2[k * 64 + tid];
        c2[tid] = LRELU(s);
    }
    if (tid < 32) {
        float s = e2_b2[tid];
        for (int k = 0; k < 64; ++k) s += e2_b1[k] * e2_w2[k * 32 + tid];
        c3[tid] = LRELU(s);
    }
    if (tid < 32) {
        float s = e3_b2[tid];
        for (int k = 0; k < 64; ++k) s += e3_b1[k] * e3_w2[k * 32 + tid];
        c4[tid] = LRELU(s);
    }
    __syncthreads();
    if (tid < 64) cbuf[tid] = c1[tid];
    if (tid < 64) cbuf[64 + tid] = c2[tid];
    if (tid < 32) cbuf[128 + tid] = c3[tid];
    if (tid < 32) cbuf[160 + tid] = c4[tid];
    // m1 [128]
    {
        float s = e1_b1[tid];
        for (int f = 0; f < 64; ++f) s += c1[f] * e1_w1[f * 128 + tid];
        cbuf[192 + tid] = s;
    }
    // m2 [64]
    if (tid < 64) {
        float s = e2_b1[tid];
        for (int f = 0; f < 64; ++f) s += c2[f] * e2_w1[f * 64 + tid];
        cbuf[320 + tid] = s;
    }
    // m3 [64]
    if (tid < 64) {
        float s = e3_b1[tid];
        for (int f = 0; f < 32; ++f) s += c3[f] * e3_w1[f * 64 + tid];
        cbuf[384 + tid] = s;
    }
}

// ---------------- final: out[e] = dot(h[row]*h[col], fcw[0:32]) + dot(d[e], fcw[32:64]) + fcb
__global__ void final_k(const float* __restrict__ h3, const float* __restrict__ dv3,
                        const float* __restrict__ c4, const int* __restrict__ row,
                        const int* __restrict__ col, const float* __restrict__ fcw,
                        const float* __restrict__ fcb, float* __restrict__ out, int E, int N) {
    __shared__ float sw[64];
    __shared__ float sc4[32];
    int tid = threadIdx.x;
    if (tid < 64) sw[tid] = fcw[tid];
    if (tid < 32) sc4[tid] = c4[tid];
    __syncthreads();
    int e = blockIdx.x * blockDim.x + tid;
    if (e >= E) return;
    int r = row[e], c = col[e];
    const float4* hr = (const float4*)(h3 + (size_t)r * 32);
    const float4* hc = (const float4*)(h3 + (size_t)c * 32);
    float s = fcb[0];
#pragma unroll
    for (int q = 0; q < 8; ++q) {
        float4 a = hr[q], b = hc[q];
        s += a.x * b.x * sw[q * 4 + 0] + a.y * b.y * sw[q * 4 + 1] + a.z * b.z * sw[q * 4 + 2] +
             a.w * b.w * sw[q * 4 + 3];
    }
    if (e < N) {
        const float4* dp = (const float4*)(dv3 + (size_t)e * 32);
#pragma unroll
        for (int q = 0; q < 8; ++q) {
            float4 d = dp[q];
            s += d.x * sw[32 + q * 4 + 0] + d.y * sw[32 + q * 4 + 1] + d.z * sw[32 + q * 4 + 2] +
                 d.w * sw[32 + q * 4 + 3];
        }
    } else {
#pragma unroll
        for (int k = 0; k < 32; ++k) s += sc4[k] * sw[32 + k];
    }
    out[e] = s;
}

extern "C" void kernel_launch(void* const* d_in, const int* in_sizes, int n_in, void* d_out,
                              int out_size, void* d_ws, size_t ws_size, hipStream_t stream) {
    const float* x = (const float*)d_in[0];
    const float* dis = (const float*)d_in[1];
    const int* ei = (const int*)d_in[2];
    const float* s_wl[4] = {(const float*)d_in[3], (const float*)d_in[6], (const float*)d_in[9],
                            (const float*)d_in[12]};
    const float* s_bl[4] = {(const float*)d_in[4], (const float*)d_in[7], (const float*)d_in[10],
                            (const float*)d_in[13]};
    const float* s_wr[4] = {(const float*)d_in[5], (const float*)d_in[8], (const float*)d_in[11],
                            (const float*)d_in[14]};
    const float* e_w1[4] = {(const float*)d_in[15], (const float*)d_in[19], (const float*)d_in[23],
                            (const float*)d_in[27]};
    const float* e_b1[4] = {(const float*)d_in[16], (const float*)d_in[20], (const float*)d_in[24],
                            (const float*)d_in[28]};
    const float* e_w2[4] = {(const float*)d_in[17], (const float*)d_in[21], (const float*)d_in[25],
                            (const float*)d_in[29]};
    const float* e_b2[4] = {(const float*)d_in[18], (const float*)d_in[22], (const float*)d_in[26],
                            (const float*)d_in[30]};
    const float* fcw = (const float*)d_in[31];
    const float* fcb = (const float*)d_in[32];

    const int N = in_sizes[0] / 64;
    const int E = in_sizes[1] / 8;
    const int* row = ei;
    const int* col = ei + E;

    char* ws = (char*)d_ws;
    int* cnt = (int*)ws;
    ws += (size_t)N * 4;
    int* rowptr = (int*)ws;
    ws += (size_t)(N + 1) * 4;
    int* wp = (int*)ws;
    ws += (size_t)N * 4;
    int* ssrc = (int*)ws;
    ws += (size_t)E * 4;
    int* seid = (int*)ws;
    ws += (size_t)E * 4;
    float* acc = (float*)ws;
    ws += (size_t)N * 64 * 4;
    float* hA = (float*)ws;
    ws += (size_t)N * 64 * 4;
    float* hB = (float*)ws;
    ws += (size_t)N * 64 * 4;
    float* dvA = (float*)ws;
    ws += (size_t)N * 64 * 4;
    float* dvB = (float*)ws;
    ws += (size_t)N * 64 * 4;
    float* cbuf = (float*)ws;

    // ---- degree histogram + CSR build (shared by SAGE and edge convs)
    hipMemsetAsync(cnt, 0, (size_t)N * 4, stream);
    hist_k<<<(E + 255) / 256, 256, 0, stream>>>(col, cnt, E);
    scan_k<<<1, 1024, 0, stream>>>(cnt, rowptr, wp, N);
    csr_build_k<<<(E + 255) / 256, 256, 0, stream>>>(row, col, wp, ssrc, seid, E);

    // ---- constants for edge-conv decomposition (independent; overlap early)
    consts_k<<<1, 128, 0, stream>>>(e_b1[0], e_w2[0], e_b2[0], e_w1[1], e_b1[1], e_w2[1], e_b2[1],
                                    e_w1[2], e_b1[2], e_w2[2], e_b2[2], e_w1[3], e_b1[3], e_w2[3],
                                    e_b2[3], cbuf);

    const int WPB = 4;  // waves per 256-thread block

    // ---- SAGE layer 0: x -> hA (64->64)
    sage_aggr64_k<<<(N + WPB - 1) / WPB, 256, 0, stream>>>(x, rowptr, ssrc, acc, N);
    sage_compute_k<64, 64><<<(N + 3) / 4, dim3(64, 4), 0, stream>>>(acc, cnt, x, s_wl[0], s_bl[0],
                                                                    s_wr[0], hA, N);
    // ---- SAGE layer 1: hA -> hB (64->64)
    sage_aggr64_k<<<(N + WPB - 1) / WPB, 256, 0, stream>>>(hA, rowptr, ssrc, acc, N);
    sage_compute_k<64, 64><<<(N + 3) / 4, dim3(64, 4), 0, stream>>>(acc, cnt, hA, s_wl[1], s_bl[1],
                                                                    s_wr[1], hB, N);
    // ---- SAGE layer 2: hB -> hA (64->32)
    sage_aggr64_k<<<(N + WPB - 1) / WPB, 256, 0, stream>>>(hB, rowptr, ssrc, acc, N);
    sage_compute_k<64, 32><<<(N + 7) / 8, dim3(32, 8), 0, stream>>>(acc, cnt, hB, s_wl[2], s_bl[2],
                                                                    s_wr[2], hA, N);
    // ---- SAGE layer 3: hA -> hB (32->32)
    sage_aggr32_k<<<(N + WPB - 1) / WPB, 256, 0, stream>>>(hA, rowptr, ssrc, acc, N);
    sage_compute_k<32, 32><<<(N + 7) / 8, dim3(32, 8), 0, stream>>>(acc, cnt, hA, s_wl[3], s_bl[3],
                                                                    s_wr[3], hB, N);

    // ---- edge conv layer 0: dis -> dvA (varying rows t<N only; rows>=N are c1)
    edge_aggr8_k<<<(N + WPB - 1) / WPB, 256, 0, stream>>>(dis, rowptr, seid, acc, N);
    edge_compute_k<8, 128, 64><<<N, 128, 0, stream>>>(acc, cnt, e_b1[0], e_w1[0], e_b1[0], e_w2[0],
                                                      e_b2[0], dvA, N);
    // ---- edge conv layer 1: dvA (+c1) -> dvB
    edge_aggr_delta64_k<<<(N + WPB - 1) / WPB, 256, 0, stream>>>(dvA, cbuf + 0, rowptr, seid, acc,
                                                                 N);
    edge_compute_k<64, 128, 64><<<N, 128, 0, stream>>>(acc, cnt, cbuf + 192, e_w1[1], e_b1[1],
                                                       e_w2[1], e_b2[1], dvB, N);
    // ---- edge conv layer 2: dvB (+c2) -> dvA (width 32 out)
    edge_aggr_delta64_k<<<(N + WPB - 1) / WPB, 256, 0, stream>>>(dvB, cbuf + 64, rowptr, seid, acc,
                                                                 N);
    edge_compute_k<64, 64, 32><<<N, 64, 0, stream>>>(acc, cnt, cbuf + 320, e_w1[2], e_b1[2],
                                                     e_w2[2], e_b2[2], dvA, N);
    // ---- edge conv layer 3: dvA (+c3) -> dvB (width 32 out)
    edge_aggr_delta32_k<<<(N + WPB - 1) / WPB, 256, 0, stream>>>(dvA, cbuf + 128, rowptr, seid, acc,
                                                                 N);
    edge_compute_k<32, 64, 32><<<N, 64, 0, stream>>>(acc, cnt, cbuf + 384, e_w1[3], e_b1[3],
                                                     e_w2[3], e_b2[3], dvB, N);

    // ---- final per-edge output
    final_k<<<(E + 255) / 256, 256, 0, stream>>>(hB, dvB, cbuf + 160, row, col, fcw, fcb,
                                                 (float*)d_out, E, N);
}

// Round 3
// 1021.035 us; speedup vs baseline: 1.3286x; 1.1012x over previous
//
#include <hip/hip_runtime.h>

#define LRELU(v) ((v) > 0.0f ? (v) : 0.01f * (v))

// ---------------- histogram of col (in-degree) -------------------------------
__global__ void hist_k(const int* __restrict__ col, int* __restrict__ cnt, int E) {
    int e = blockIdx.x * blockDim.x + threadIdx.x;
    if (e < E) atomicAdd(&cnt[col[e]], 1);
}

// ---------------- hierarchical scan: (1) per-block sums ----------------------
__global__ void blocksum_k(const int* __restrict__ cnt, int* __restrict__ bsum, int N) {
    __shared__ int ws[4];
    int tid = threadIdx.x;
    int i = blockIdx.x * 256 + tid;
    int v = (i < N) ? cnt[i] : 0;
    for (int off = 32; off > 0; off >>= 1) v += __shfl_down(v, off);
    if ((tid & 63) == 0) ws[tid >> 6] = v;
    __syncthreads();
    if (tid == 0) bsum[blockIdx.x] = ws[0] + ws[1] + ws[2] + ws[3];
}

// ---------------- (2) exclusive scan of block sums (NB <= 256) ---------------
__global__ void scanbsum_k(int* __restrict__ bsum, int NB) {
    __shared__ int s[256];
    int tid = threadIdx.x;
    int v = (tid < NB) ? bsum[tid] : 0;
    s[tid] = v;
    __syncthreads();
    for (int off = 1; off < 256; off <<= 1) {
        int t = (tid >= off) ? s[tid - off] : 0;
        __syncthreads();
        s[tid] += t;
        __syncthreads();
    }
    if (tid < NB) bsum[tid] = s[tid] - v;  // exclusive
}

// ---------------- (3) per-block local exclusive scan + offset ----------------
__global__ void rowptr_k(const int* __restrict__ cnt, const int* __restrict__ bsum,
                         int* __restrict__ rowptr, int* __restrict__ wp, int N) {
    __shared__ int s[256];
    int tid = threadIdx.x;
    int i = blockIdx.x * 256 + tid;
    int v = (i < N) ? cnt[i] : 0;
    s[tid] = v;
    __syncthreads();
    for (int off = 1; off < 256; off <<= 1) {
        int t = (tid >= off) ? s[tid - off] : 0;
        __syncthreads();
        s[tid] += t;
        __syncthreads();
    }
    int ex = s[tid] - v + bsum[blockIdx.x];
    if (i < N) {
        rowptr[i] = ex;
        wp[i] = ex;
        if (i == N - 1) rowptr[N] = ex + v;
    }
}

// ---------------- CSR build: place (row[e], e) into slot for col[e] ----------
__global__ void csr_build_k(const int* __restrict__ row, const int* __restrict__ col,
                            int* __restrict__ wp, int* __restrict__ ssrc,
                            int* __restrict__ seid, int E) {
    int e = blockIdx.x * blockDim.x + threadIdx.x;
    if (e >= E) return;
    int pos = atomicAdd(&wp[col[e]], 1);
    ssrc[pos] = row[e];
    seid[pos] = e;
}

// ---------------- SAGE aggregate (gather), 64-wide: one wave per node --------
__global__ void sage_aggr64_k(const float* __restrict__ h, const int* __restrict__ rowptr,
                              const int* __restrict__ ssrc, float* __restrict__ acc, int N) {
    int wave = (blockIdx.x * blockDim.x + threadIdx.x) >> 6;
    int lane = threadIdx.x & 63;
    if (wave >= N) return;
    int s = rowptr[wave], e = rowptr[wave + 1];
    float a = 0.0f;
    int p = s;
    for (; p + 1 < e; p += 2) {
        int s0 = ssrc[p], s1 = ssrc[p + 1];
        a += h[(size_t)s0 * 64 + lane] + h[(size_t)s1 * 64 + lane];
    }
    if (p < e) a += h[(size_t)ssrc[p] * 64 + lane];
    acc[(size_t)wave * 64 + lane] = a;
}

// ---------------- SAGE aggregate, 32-wide: wave handles 2 neighbors at once --
__global__ void sage_aggr32_k(const float* __restrict__ h, const int* __restrict__ rowptr,
                              const int* __restrict__ ssrc, float* __restrict__ acc, int N) {
    int wave = (blockIdx.x * blockDim.x + threadIdx.x) >> 6;
    int lane = threadIdx.x & 63;
    if (wave >= N) return;
    int f = lane & 31, u = lane >> 5;
    int s = rowptr[wave], e = rowptr[wave + 1];
    float a = 0.0f;
    for (int p = s + u; p < e; p += 2) a += h[(size_t)ssrc[p] * 32 + f];
    a += __shfl_down(a, 32);
    if (u == 0) acc[(size_t)wave * 32 + f] = a;
}

// ---------------- SAGE: out = leaky(mean@wl + bl + h@wr) ---------------------
template <int FIN, int FOUT>
__global__ void sage_compute_k(const float* __restrict__ acc, const int* __restrict__ cnt,
                               const float* __restrict__ h, const float* __restrict__ wl,
                               const float* __restrict__ bl, const float* __restrict__ wr,
                               float* __restrict__ out, int N) {
    constexpr int NPB = 256 / FOUT;
    __shared__ float swl[FIN * FOUT];
    __shared__ float swr[FIN * FOUT];
    int lin = threadIdx.y * FOUT + threadIdx.x;
    for (int idx = lin; idx < FIN * FOUT; idx += 256) {
        swl[idx] = wl[idx];
        swr[idx] = wr[idx];
    }
    __syncthreads();
    int i = blockIdx.x * NPB + threadIdx.y;
    if (i >= N) return;
    int o = threadIdx.x;
    float inv = 1.0f / fmaxf((float)cnt[i], 1.0f);
    float s = bl[o];
    for (int f = 0; f < FIN; ++f) {
        s += acc[i * FIN + f] * inv * swl[f * FOUT + o] + h[i * FIN + f] * swr[f * FOUT + o];
    }
    out[i * FOUT + o] = LRELU(s);
}

// ---------------- edge conv layer 0 aggregate: sum dis[eid] (8-wide) ---------
__global__ void edge_aggr8_k(const float* __restrict__ dis, const int* __restrict__ rowptr,
                             const int* __restrict__ seid, float* __restrict__ sd, int N) {
    int wave = (blockIdx.x * blockDim.x + threadIdx.x) >> 6;
    int lane = threadIdx.x & 63;
    if (wave >= N) return;
    int f = lane & 7, u = lane >> 3;  // 8 neighbors in parallel
    int s = rowptr[wave], e = rowptr[wave + 1];
    float a = 0.0f;
    for (int p = s + u; p < e; p += 8) a += dis[(size_t)seid[p] * 8 + f];
    a += __shfl_down(a, 32);
    a += __shfl_down(a, 16);
    a += __shfl_down(a, 8);
    if (lane < 8) sd[(size_t)wave * 8 + lane] = a;
}

// ---------------- edge conv layers 1-3 aggregate: sum (dv[eid]-c), eid<N -----
__global__ void edge_aggr_delta64_k(const float* __restrict__ dv, const float* __restrict__ cvec,
                                    const int* __restrict__ rowptr, const int* __restrict__ seid,
                                    float* __restrict__ sd, int N) {
    int wave = (blockIdx.x * blockDim.x + threadIdx.x) >> 6;
    int lane = threadIdx.x & 63;
    if (wave >= N) return;
    float c = cvec[lane];
    int s = rowptr[wave], e = rowptr[wave + 1];
    float a = 0.0f;
    for (int p = s; p < e; ++p) {
        int eid = seid[p];
        if (eid < N) a += dv[(size_t)eid * 64 + lane] - c;
    }
    sd[(size_t)wave * 64 + lane] = a;
}

__global__ void edge_aggr_delta32_k(const float* __restrict__ dv, const float* __restrict__ cvec,
                                    const int* __restrict__ rowptr, const int* __restrict__ seid,
                                    float* __restrict__ sd, int N) {
    int wave = (blockIdx.x * blockDim.x + threadIdx.x) >> 6;
    int lane = threadIdx.x & 63;
    if (wave >= N) return;
    int f = lane & 31, u = lane >> 5;
    float c = cvec[f];
    int s = rowptr[wave], e = rowptr[wave + 1];
    float a = 0.0f;
    for (int p = s + u; p < e; p += 2) {
        int eid = seid[p];
        if (eid < N) a += dv[(size_t)eid * 32 + f] - c;
    }
    a += __shfl_down(a, 32);
    if (u == 0) sd[(size_t)wave * 32 + f] = a;
}

// ---------------- edge conv compute for rows t<N -----------------------------
template <int HIN, int H2, int HOUT>
__global__ void edge_compute_k(const float* __restrict__ sd, const int* __restrict__ cnt,
                               const float* __restrict__ m, const float* __restrict__ w1,
                               const float* __restrict__ b1, const float* __restrict__ w2,
                               const float* __restrict__ b2, float* __restrict__ out, int N) {
    __shared__ float aggr[H2];
    __shared__ float ssd[HIN];
    int t = blockIdx.x;
    int tid = threadIdx.x;  // H2 threads
    float deg = (float)cnt[t];
    float inv = 1.0f / (deg + 1.0f);
    for (int f = tid; f < HIN; f += H2) ssd[f] = sd[t * HIN + f];
    __syncthreads();
    float s = deg * m[tid] + b1[tid];
    for (int f = 0; f < HIN; ++f) s += ssd[f] * w1[f * H2 + tid];
    aggr[tid] = s * inv;
    __syncthreads();
    if (tid < HOUT) {
        float o = b2[tid];
        for (int k = 0; k < H2; ++k) o += aggr[k] * w2[k * HOUT + tid];
        out[t * HOUT + tid] = LRELU(o);
    }
}

// ---------------- constants: c_{l+1} = leaky(b1_l@w2_l + b2_l), m_l = c_l@w1_l + b1_l
__global__ void consts_k(const float* __restrict__ e0_b1, const float* __restrict__ e0_w2,
                         const float* __restrict__ e0_b2, const float* __restrict__ e1_w1,
                         const float* __restrict__ e1_b1, const float* __restrict__ e1_w2,
                         const float* __restrict__ e1_b2, const float* __restrict__ e2_w1,
                         const float* __restrict__ e2_b1, const float* __restrict__ e2_w2,
                         const float* __restrict__ e2_b2, const float* __restrict__ e3_w1,
                         const float* __restrict__ e3_b1, const float* __restrict__ e3_w2,
                         const float* __restrict__ e3_b2, float* __restrict__ cbuf) {
    __shared__ float c1[64], c2[64], c3[32], c4[32];
    int tid = threadIdx.x;  // 128 threads
    if (tid < 64) {
        float s = e0_b2[tid];
        for (int k = 0; k < 128; ++k) s += e0_b1[k] * e0_w2[k * 64 + tid];
        c1[tid] = LRELU(s);
    }
    if (tid < 64) {
        float s = e1_b2[tid];
        for (int k = 0; k < 128; ++k) s += e1_b1[k] * e1_w2[k * 64 + tid];
        c2[tid] = LRELU(s);
    }
    if (tid < 32) {
        float s = e2_b2[tid];
        for (int k = 0; k < 64; ++k) s += e2_b1[k] * e2_w2[k * 32 + tid];
        c3[tid] = LRELU(s);
    }
    if (tid < 32) {
        float s = e3_b2[tid];
        for (int k = 0; k < 64; ++k) s += e3_b1[k] * e3_w2[k * 32 + tid];
        c4[tid] = LRELU(s);
    }
    __syncthreads();
    if (tid < 64) cbuf[tid] = c1[tid];
    if (tid < 64) cbuf[64 + tid] = c2[tid];
    if (tid < 32) cbuf[128 + tid] = c3[tid];
    if (tid < 32) cbuf[160 + tid] = c4[tid];
    // m1 [128]
    {
        float s = e1_b1[tid];
        for (int f = 0; f < 64; ++f) s += c1[f] * e1_w1[f * 128 + tid];
        cbuf[192 + tid] = s;
    }
    // m2 [64]
    if (tid < 64) {
        float s = e2_b1[tid];
        for (int f = 0; f < 64; ++f) s += c2[f] * e2_w1[f * 64 + tid];
        cbuf[320 + tid] = s;
    }
    // m3 [64]
    if (tid < 64) {
        float s = e3_b1[tid];
        for (int f = 0; f < 32; ++f) s += c3[f] * e3_w1[f * 64 + tid];
        cbuf[384 + tid] = s;
    }
}

// ---------------- final: out[e] = dot(h[row]*h[col], fcw[0:32]) + dot(d[e], fcw[32:64]) + fcb
__global__ void final_k(const float* __restrict__ h3, const float* __restrict__ dv3,
                        const float* __restrict__ c4, const int* __restrict__ row,
                        const int* __restrict__ col, const float* __restrict__ fcw,
                        const float* __restrict__ fcb, float* __restrict__ out, int E, int N) {
    __shared__ float sw[64];
    __shared__ float sc4[32];
    int tid = threadIdx.x;
    if (tid < 64) sw[tid] = fcw[tid];
    if (tid < 32) sc4[tid] = c4[tid];
    __syncthreads();
    int e = blockIdx.x * blockDim.x + tid;
    if (e >= E) return;
    int r = row[e], c = col[e];
    const float4* hr = (const float4*)(h3 + (size_t)r * 32);
    const float4* hc = (const float4*)(h3 + (size_t)c * 32);
    float s = fcb[0];
#pragma unroll
    for (int q = 0; q < 8; ++q) {
        float4 a = hr[q], b = hc[q];
        s += a.x * b.x * sw[q * 4 + 0] + a.y * b.y * sw[q * 4 + 1] + a.z * b.z * sw[q * 4 + 2] +
             a.w * b.w * sw[q * 4 + 3];
    }
    if (e < N) {
        const float4* dp = (const float4*)(dv3 + (size_t)e * 32);
#pragma unroll
        for (int q = 0; q < 8; ++q) {
            float4 d = dp[q];
            s += d.x * sw[32 + q * 4 + 0] + d.y * sw[32 + q * 4 + 1] + d.z * sw[32 + q * 4 + 2] +
                 d.w * sw[32 + q * 4 + 3];
        }
    } else {
#pragma unroll
        for (int k = 0; k < 32; ++k) s += sc4[k] * sw[32 + k];
    }
    out[e] = s;
}

extern "C" void kernel_launch(void* const* d_in, const int* in_sizes, int n_in, void* d_out,
                              int out_size, void* d_ws, size_t ws_size, hipStream_t stream) {
    const float* x = (const float*)d_in[0];
    const float* dis = (const float*)d_in[1];
    const int* ei = (const int*)d_in[2];
    const float* s_wl[4] = {(const float*)d_in[3], (const float*)d_in[6], (const float*)d_in[9],
                            (const float*)d_in[12]};
    const float* s_bl[4] = {(const float*)d_in[4], (const float*)d_in[7], (const float*)d_in[10],
                            (const float*)d_in[13]};
    const float* s_wr[4] = {(const float*)d_in[5], (const float*)d_in[8], (const float*)d_in[11],
                            (const float*)d_in[14]};
    const float* e_w1[4] = {(const float*)d_in[15], (const float*)d_in[19], (const float*)d_in[23],
                            (const float*)d_in[27]};
    const float* e_b1[4] = {(const float*)d_in[16], (const float*)d_in[20], (const float*)d_in[24],
                            (const float*)d_in[28]};
    const float* e_w2[4] = {(const float*)d_in[17], (const float*)d_in[21], (const float*)d_in[25],
                            (const float*)d_in[29]};
    const float* e_b2[4] = {(const float*)d_in[18], (const float*)d_in[22], (const float*)d_in[26],
                            (const float*)d_in[30]};
    const float* fcw = (const float*)d_in[31];
    const float* fcb = (const float*)d_in[32];

    const int N = in_sizes[0] / 64;
    const int E = in_sizes[1] / 8;
    const int* row = ei;
    const int* col = ei + E;
    const int NB = (N + 255) / 256;  // 196 for N=50000

    char* ws = (char*)d_ws;
    int* cnt = (int*)ws;
    ws += (size_t)N * 4;
    int* rowptr = (int*)ws;
    ws += (size_t)(N + 1) * 4;
    int* wp = (int*)ws;
    ws += (size_t)N * 4;
    int* bsum = (int*)ws;
    ws += (size_t)256 * 4;
    int* ssrc = (int*)ws;
    ws += (size_t)E * 4;
    int* seid = (int*)ws;
    ws += (size_t)E * 4;
    float* acc = (float*)ws;
    ws += (size_t)N * 64 * 4;
    float* hA = (float*)ws;
    ws += (size_t)N * 64 * 4;
    float* hB = (float*)ws;
    ws += (size_t)N * 64 * 4;
    float* dvA = (float*)ws;
    ws += (size_t)N * 64 * 4;
    float* dvB = (float*)ws;
    ws += (size_t)N * 64 * 4;
    float* cbuf = (float*)ws;

    // ---- degree histogram + hierarchical-scan CSR build
    hipMemsetAsync(cnt, 0, (size_t)N * 4, stream);
    hist_k<<<(E + 255) / 256, 256, 0, stream>>>(col, cnt, E);
    blocksum_k<<<NB, 256, 0, stream>>>(cnt, bsum, N);
    scanbsum_k<<<1, 256, 0, stream>>>(bsum, NB);
    rowptr_k<<<NB, 256, 0, stream>>>(cnt, bsum, rowptr, wp, N);
    csr_build_k<<<(E + 255) / 256, 256, 0, stream>>>(row, col, wp, ssrc, seid, E);

    // ---- constants for edge-conv decomposition
    consts_k<<<1, 128, 0, stream>>>(e_b1[0], e_w2[0], e_b2[0], e_w1[1], e_b1[1], e_w2[1], e_b2[1],
                                    e_w1[2], e_b1[2], e_w2[2], e_b2[2], e_w1[3], e_b1[3], e_w2[3],
                                    e_b2[3], cbuf);

    const int WPB = 4;  // waves per 256-thread block

    // ---- SAGE layer 0: x -> hA (64->64)
    sage_aggr64_k<<<(N + WPB - 1) / WPB, 256, 0, stream>>>(x, rowptr, ssrc, acc, N);
    sage_compute_k<64, 64><<<(N + 3) / 4, dim3(64, 4), 0, stream>>>(acc, cnt, x, s_wl[0], s_bl[0],
                                                                    s_wr[0], hA, N);
    // ---- SAGE layer 1: hA -> hB (64->64)
    sage_aggr64_k<<<(N + WPB - 1) / WPB, 256, 0, stream>>>(hA, rowptr, ssrc, acc, N);
    sage_compute_k<64, 64><<<(N + 3) / 4, dim3(64, 4), 0, stream>>>(acc, cnt, hA, s_wl[1], s_bl[1],
                                                                    s_wr[1], hB, N);
    // ---- SAGE layer 2: hB -> hA (64->32)
    sage_aggr64_k<<<(N + WPB - 1) / WPB, 256, 0, stream>>>(hB, rowptr, ssrc, acc, N);
    sage_compute_k<64, 32><<<(N + 7) / 8, dim3(32, 8), 0, stream>>>(acc, cnt, hB, s_wl[2], s_bl[2],
                                                                    s_wr[2], hA, N);
    // ---- SAGE layer 3: hA -> hB (32->32)
    sage_aggr32_k<<<(N + WPB - 1) / WPB, 256, 0, stream>>>(hA, rowptr, ssrc, acc, N);
    sage_compute_k<32, 32><<<(N + 7) / 8, dim3(32, 8), 0, stream>>>(acc, cnt, hA, s_wl[3], s_bl[3],
                                                                    s_wr[3], hB, N);

    // ---- edge conv layer 0: dis -> dvA
    edge_aggr8_k<<<(N + WPB - 1) / WPB, 256, 0, stream>>>(dis, rowptr, seid, acc, N);
    edge_compute_k<8, 128, 64><<<N, 128, 0, stream>>>(acc, cnt, e_b1[0], e_w1[0], e_b1[0], e_w2[0],
                                                      e_b2[0], dvA, N);
    // ---- edge conv layer 1: dvA (+c1) -> dvB
    edge_aggr_delta64_k<<<(N + WPB - 1) / WPB, 256, 0, stream>>>(dvA, cbuf + 0, rowptr, seid, acc,
                                                                 N);
    edge_compute_k<64, 128, 64><<<N, 128, 0, stream>>>(acc, cnt, cbuf + 192, e_w1[1], e_b1[1],
                                                       e_w2[1], e_b2[1], dvB, N);
    // ---- edge conv layer 2: dvB (+c2) -> dvA (width 32 out)
    edge_aggr_delta64_k<<<(N + WPB - 1) / WPB, 256, 0, stream>>>(dvB, cbuf + 64, rowptr, seid, acc,
                                                                 N);
    edge_compute_k<64, 64, 32><<<N, 64, 0, stream>>>(acc, cnt, cbuf + 320, e_w1[2], e_b1[2],
                                                     e_w2[2], e_b2[2], dvA, N);
    // ---- edge conv layer 3: dvA (+c3) -> dvB (width 32 out)
    edge_aggr_delta32_k<<<(N + WPB - 1) / WPB, 256, 0, stream>>>(dvA, cbuf + 128, rowptr, seid, acc,
                                                                 N);
    edge_compute_k<32, 64, 32><<<N, 64, 0, stream>>>(acc, cnt, cbuf + 384, e_w1[3], e_b1[3],
                                                     e_w2[3], e_b2[3], dvB, N);

    // ---- final per-edge output
    final_k<<<(E + 255) / 256, 256, 0, stream>>>(hB, dvB, cbuf + 160, row, col, fcw, fcb,
                                                 (float*)d_out, E, N);
}

// Round 5
// 884.543 us; speedup vs baseline: 1.5336x; 1.1543x over previous
//
#include <hip/hip_runtime.h>

#define LRELU(v) ((v) > 0.0f ? (v) : 0.01f * (v))

// ---------------- histogram of col (in-degree) -------------------------------
__global__ void hist_k(const int* __restrict__ col, int* __restrict__ cnt, int E) {
    int e = blockIdx.x * blockDim.x + threadIdx.x;
    if (e < E) atomicAdd(&cnt[col[e]], 1);
}

// ---------------- hierarchical scan: (1) per-block sums ----------------------
__global__ void blocksum_k(const int* __restrict__ cnt, int* __restrict__ bsum, int N) {
    __shared__ int ws[4];
    int tid = threadIdx.x;
    int i = blockIdx.x * 256 + tid;
    int v = (i < N) ? cnt[i] : 0;
    for (int off = 32; off > 0; off >>= 1) v += __shfl_down(v, off);
    if ((tid & 63) == 0) ws[tid >> 6] = v;
    __syncthreads();
    if (tid == 0) bsum[blockIdx.x] = ws[0] + ws[1] + ws[2] + ws[3];
}

// ---------------- (2) exclusive scan of block sums (NB <= 256) ---------------
__global__ void scanbsum_k(int* __restrict__ bsum, int NB) {
    __shared__ int s[256];
    int tid = threadIdx.x;
    int v = (tid < NB) ? bsum[tid] : 0;
    s[tid] = v;
    __syncthreads();
    for (int off = 1; off < 256; off <<= 1) {
        int t = (tid >= off) ? s[tid - off] : 0;
        __syncthreads();
        s[tid] += t;
        __syncthreads();
    }
    if (tid < NB) bsum[tid] = s[tid] - v;  // exclusive
}

// ---------------- (3) per-block local exclusive scan + offset ----------------
__global__ void rowptr_k(const int* __restrict__ cnt, const int* __restrict__ bsum,
                         int* __restrict__ rowptr, int* __restrict__ wp, int N) {
    __shared__ int s[256];
    int tid = threadIdx.x;
    int i = blockIdx.x * 256 + tid;
    int v = (i < N) ? cnt[i] : 0;
    s[tid] = v;
    __syncthreads();
    for (int off = 1; off < 256; off <<= 1) {
        int t = (tid >= off) ? s[tid - off] : 0;
        __syncthreads();
        s[tid] += t;
        __syncthreads();
    }
    int ex = s[tid] - v + bsum[blockIdx.x];
    if (i < N) {
        rowptr[i] = ex;
        wp[i] = ex;
        if (i == N - 1) rowptr[N] = ex + v;
    }
}

// ---------------- CSR build: place (row[e], e) into slot for col[e] ----------
__global__ void csr_build_k(const int* __restrict__ row, const int* __restrict__ col,
                            int* __restrict__ wp, int* __restrict__ ssrc,
                            int* __restrict__ seid, int E) {
    int e = blockIdx.x * blockDim.x + threadIdx.x;
    if (e >= E) return;
    int pos = atomicAdd(&wp[col[e]], 1);
    ssrc[pos] = row[e];
    seid[pos] = e;
}

// ---------------- SAGE aggregate (gather), 64-wide: one wave per node --------
__global__ void sage_aggr64_k(const float* __restrict__ h, const int* __restrict__ rowptr,
                              const int* __restrict__ ssrc, float* __restrict__ acc, int N) {
    int wave = (blockIdx.x * blockDim.x + threadIdx.x) >> 6;
    int lane = threadIdx.x & 63;
    if (wave >= N) return;
    int s = rowptr[wave], e = rowptr[wave + 1];
    float a = 0.0f;
    int p = s;
    for (; p + 1 < e; p += 2) {
        int s0 = ssrc[p], s1 = ssrc[p + 1];
        a += h[(size_t)s0 * 64 + lane] + h[(size_t)s1 * 64 + lane];
    }
    if (p < e) a += h[(size_t)ssrc[p] * 64 + lane];
    acc[(size_t)wave * 64 + lane] = a;
}

// ---------------- SAGE aggregate, 32-wide: wave handles 2 neighbors at once --
__global__ void sage_aggr32_k(const float* __restrict__ h, const int* __restrict__ rowptr,
                              const int* __restrict__ ssrc, float* __restrict__ acc, int N) {
    int wave = (blockIdx.x * blockDim.x + threadIdx.x) >> 6;
    int lane = threadIdx.x & 63;
    if (wave >= N) return;
    int f = lane & 31, u = lane >> 5;
    int s = rowptr[wave], e = rowptr[wave + 1];
    float a = 0.0f;
    for (int p = s + u; p < e; p += 2) a += h[(size_t)ssrc[p] * 32 + f];
    a += __shfl_down(a, 32);
    if (u == 0) acc[(size_t)wave * 32 + f] = a;
}

// ---------------- SAGE: out = leaky(mean@wl + bl + h@wr) ---------------------
template <int FIN, int FOUT>
__global__ void sage_compute_k(const float* __restrict__ acc, const int* __restrict__ cnt,
                               const float* __restrict__ h, const float* __restrict__ wl,
                               const float* __restrict__ bl, const float* __restrict__ wr,
                               float* __restrict__ out, int N) {
    constexpr int NPB = 256 / FOUT;
    __shared__ float swl[FIN * FOUT];
    __shared__ float swr[FIN * FOUT];
    int lin = threadIdx.y * FOUT + threadIdx.x;
    for (int idx = lin; idx < FIN * FOUT; idx += 256) {
        swl[idx] = wl[idx];
        swr[idx] = wr[idx];
    }
    __syncthreads();
    int i = blockIdx.x * NPB + threadIdx.y;
    if (i >= N) return;
    int o = threadIdx.x;
    float inv = 1.0f / fmaxf((float)cnt[i], 1.0f);
    float s = bl[o];
    for (int f = 0; f < FIN; ++f) {
        s += acc[i * FIN + f] * inv * swl[f * FOUT + o] + h[i * FIN + f] * swr[f * FOUT + o];
    }
    out[i * FOUT + o] = LRELU(s);
}

// ---------------- edge conv layer 0 aggregate: sum dis[eid] (8-wide) ---------
__global__ void edge_aggr8_k(const float* __restrict__ dis, const int* __restrict__ rowptr,
                             const int* __restrict__ seid, float* __restrict__ sd, int N) {
    int wave = (blockIdx.x * blockDim.x + threadIdx.x) >> 6;
    int lane = threadIdx.x & 63;
    if (wave >= N) return;
    int f = lane & 7, u = lane >> 3;  // 8 neighbors in parallel
    int s = rowptr[wave], e = rowptr[wave + 1];
    float a = 0.0f;
    for (int p = s + u; p < e; p += 8) a += dis[(size_t)seid[p] * 8 + f];
    a += __shfl_down(a, 32);
    a += __shfl_down(a, 16);
    a += __shfl_down(a, 8);
    if (lane < 8) sd[(size_t)wave * 8 + lane] = a;
}

// ---------------- edge conv layers 1-3 aggregate: sum (dv[eid]-c), eid<N -----
__global__ void edge_aggr_delta64_k(const float* __restrict__ dv, const float* __restrict__ cvec,
                                    const int* __restrict__ rowptr, const int* __restrict__ seid,
                                    float* __restrict__ sd, int N) {
    int wave = (blockIdx.x * blockDim.x + threadIdx.x) >> 6;
    int lane = threadIdx.x & 63;
    if (wave >= N) return;
    float c = cvec[lane];
    int s = rowptr[wave], e = rowptr[wave + 1];
    float a = 0.0f;
    for (int p = s; p < e; ++p) {
        int eid = seid[p];
        if (eid < N) a += dv[(size_t)eid * 64 + lane] - c;
    }
    sd[(size_t)wave * 64 + lane] = a;
}

__global__ void edge_aggr_delta32_k(const float* __restrict__ dv, const float* __restrict__ cvec,
                                    const int* __restrict__ rowptr, const int* __restrict__ seid,
                                    float* __restrict__ sd, int N) {
    int wave = (blockIdx.x * blockDim.x + threadIdx.x) >> 6;
    int lane = threadIdx.x & 63;
    if (wave >= N) return;
    int f = lane & 31, u = lane >> 5;
    float c = cvec[f];
    int s = rowptr[wave], e = rowptr[wave + 1];
    float a = 0.0f;
    for (int p = s + u; p < e; p += 2) {
        int eid = seid[p];
        if (eid < N) a += dv[(size_t)eid * 32 + f] - c;
    }
    a += __shfl_down(a, 32);
    if (u == 0) sd[(size_t)wave * 32 + f] = a;
}

// ---------------- W12 = w1 @ w2 (tiny weight-only GEMM) ----------------------
template <int H2, int HOUT>
__global__ void gemm_w12_k(const float* __restrict__ w1, const float* __restrict__ w2,
                           float* __restrict__ w12) {
    int i = blockIdx.x;   // row of w1 (HIN)
    int o = threadIdx.x;  // col of w2 (HOUT)
    float s = 0.0f;
    for (int k = 0; k < H2; ++k) s += w1[i * H2 + k] * w2[k * HOUT + o];
    w12[i * HOUT + o] = s;
}

// ---------------- collapsed edge conv: out = leaky(inv*(deg*mw2 + b1w2 + sd@W12) + b2)
template <int FIN, int FOUT>
__global__ void edge_compute2_k(const float* __restrict__ sd, const int* __restrict__ cnt,
                                const float* __restrict__ w12, const float* __restrict__ mw2,
                                const float* __restrict__ b1w2, const float* __restrict__ b2,
                                float* __restrict__ out, int N) {
    constexpr int NPB = 256 / FOUT;
    __shared__ float sw[FIN * FOUT];
    int lin = threadIdx.y * FOUT + threadIdx.x;
    for (int idx = lin; idx < FIN * FOUT; idx += 256) sw[idx] = w12[idx];
    __syncthreads();
    int i = blockIdx.x * NPB + threadIdx.y;
    if (i >= N) return;
    int o = threadIdx.x;
    float deg = (float)cnt[i];
    float inv = 1.0f / (deg + 1.0f);
    float s = deg * mw2[o] + b1w2[o];
    for (int f = 0; f < FIN; ++f) s += sd[i * FIN + f] * sw[f * FOUT + o];
    out[i * FOUT + o] = LRELU(s * inv + b2[o]);
}

// ---------------- constants: c_{l+1} = leaky(b1w2_l + b2_l), mw2_l = c_l@W12_l + b1w2_l
__global__ void consts_k(const float* __restrict__ e0_b1, const float* __restrict__ e0_w2,
                         const float* __restrict__ e0_b2, const float* __restrict__ e1_b1,
                         const float* __restrict__ e1_w2, const float* __restrict__ e1_b2,
                         const float* __restrict__ e2_b1, const float* __restrict__ e2_w2,
                         const float* __restrict__ e2_b2, const float* __restrict__ e3_b1,
                         const float* __restrict__ e3_w2, const float* __restrict__ e3_b2,
                         const float* __restrict__ w12_1, const float* __restrict__ w12_2,
                         const float* __restrict__ w12_3, float* __restrict__ cbuf) {
    __shared__ float c1[64], c2[64], c3[32];
    int tid = threadIdx.x;  // 128 threads
    if (tid < 64) {
        float s = 0.0f;
        for (int k = 0; k < 128; ++k) s += e0_b1[k] * e0_w2[k * 64 + tid];
        cbuf[192 + tid] = s;  // b1w2_0 == mw2_0
        c1[tid] = LRELU(s + e0_b2[tid]);
        cbuf[tid] = c1[tid];
    }
    if (tid < 64) {
        float s = 0.0f;
        for (int k = 0; k < 128; ++k) s += e1_b1[k] * e1_w2[k * 64 + tid];
        cbuf[256 + tid] = s;  // b1w2_1
        c2[tid] = LRELU(s + e1_b2[tid]);
        cbuf[64 + tid] = c2[tid];
    }
    if (tid < 32) {
        float s = 0.0f;
        for (int k = 0; k < 64; ++k) s += e2_b1[k] * e2_w2[k * 32 + tid];
        cbuf[384 + tid] = s;  // b1w2_2
        c3[tid] = LRELU(s + e2_b2[tid]);
        cbuf[128 + tid] = c3[tid];
    }
    if (tid < 32) {
        float s = 0.0f;
        for (int k = 0; k < 64; ++k) s += e3_b1[k] * e3_w2[k * 32 + tid];
        cbuf[448 + tid] = s;                      // b1w2_3
        cbuf[160 + tid] = LRELU(s + e3_b2[tid]);  // c4
    }
    __syncthreads();
    // mw2_l = c_l @ W12_l + b1w2_l
    if (tid < 64) {
        float s = cbuf[256 + tid];
        for (int f = 0; f < 64; ++f) s += c1[f] * w12_1[f * 64 + tid];
        cbuf[320 + tid] = s;  // mw2_1
    }
    if (tid < 32) {
        float s = cbuf[384 + tid];
        for (int f = 0; f < 64; ++f) s += c2[f] * w12_2[f * 32 + tid];
        cbuf[416 + tid] = s;  // mw2_2
    }
    if (tid < 32) {
        float s = cbuf[448 + tid];
        for (int f = 0; f < 32; ++f) s += c3[f] * w12_3[f * 32 + tid];
        cbuf[480 + tid] = s;  // mw2_3
    }
}

// ---------------- final: out[e] = dot(h[row]*h[col], fcw[0:32]) + dot(d[e], fcw[32:64]) + fcb
__global__ void final_k(const float* __restrict__ h3, const float* __restrict__ dv3,
                        const float* __restrict__ c4, const int* __restrict__ row,
                        const int* __restrict__ col, const float* __restrict__ fcw,
                        const float* __restrict__ fcb, float* __restrict__ out, int E, int N) {
    __shared__ float sw[64];
    __shared__ float sc4[32];
    int tid = threadIdx.x;
    if (tid < 64) sw[tid] = fcw[tid];
    if (tid < 32) sc4[tid] = c4[tid];
    __syncthreads();
    int e = blockIdx.x * blockDim.x + tid;
    if (e >= E) return;
    int r = row[e], c = col[e];
    const float4* hr = (const float4*)(h3 + (size_t)r * 32);
    const float4* hc = (const float4*)(h3 + (size_t)c * 32);
    float s = fcb[0];
#pragma unroll
    for (int q = 0; q < 8; ++q) {
        float4 a = hr[q], b = hc[q];
        s += a.x * b.x * sw[q * 4 + 0] + a.y * b.y * sw[q * 4 + 1] + a.z * b.z * sw[q * 4 + 2] +
             a.w * b.w * sw[q * 4 + 3];
    }
    if (e < N) {
        const float4* dp = (const float4*)(dv3 + (size_t)e * 32);
#pragma unroll
        for (int q = 0; q < 8; ++q) {
            float4 d = dp[q];
            s += d.x * sw[32 + q * 4 + 0] + d.y * sw[32 + q * 4 + 1] + d.z * sw[32 + q * 4 + 2] +
                 d.w * sw[32 + q * 4 + 3];
        }
    } else {
#pragma unroll
        for (int k = 0; k < 32; ++k) s += sc4[k] * sw[32 + k];
    }
    out[e] = s;
}

extern "C" void kernel_launch(void* const* d_in, const int* in_sizes, int n_in, void* d_out,
                              int out_size, void* d_ws, size_t ws_size, hipStream_t stream) {
    const float* x = (const float*)d_in[0];
    const float* dis = (const float*)d_in[1];
    const int* ei = (const int*)d_in[2];
    const float* s_wl[4] = {(const float*)d_in[3], (const float*)d_in[6], (const float*)d_in[9],
                            (const float*)d_in[12]};
    const float* s_bl[4] = {(const float*)d_in[4], (const float*)d_in[7], (const float*)d_in[10],
                            (const float*)d_in[13]};
    const float* s_wr[4] = {(const float*)d_in[5], (const float*)d_in[8], (const float*)d_in[11],
                            (const float*)d_in[14]};
    const float* e_w1[4] = {(const float*)d_in[15], (const float*)d_in[19], (const float*)d_in[23],
                            (const float*)d_in[27]};
    const float* e_b1[4] = {(const float*)d_in[16], (const float*)d_in[20], (const float*)d_in[24],
                            (const float*)d_in[28]};
    const float* e_w2[4] = {(const float*)d_in[17], (const float*)d_in[21], (const float*)d_in[25],
                            (const float*)d_in[29]};
    const float* e_b2[4] = {(const float*)d_in[18], (const float*)d_in[22], (const float*)d_in[26],
                            (const float*)d_in[30]};
    const float* fcw = (const float*)d_in[31];
    const float* fcb = (const float*)d_in[32];

    const int N = in_sizes[0] / 64;
    const int E = in_sizes[1] / 8;
    const int* row = ei;
    const int* col = ei + E;
    const int NB = (N + 255) / 256;

    char* ws = (char*)d_ws;
    int* cnt = (int*)ws;
    ws += (size_t)N * 4;
    int* rowptr = (int*)ws;
    ws += (size_t)(N + 1) * 4;
    int* wp = (int*)ws;
    ws += (size_t)N * 4;
    int* bsum = (int*)ws;
    ws += (size_t)256 * 4;
    int* ssrc = (int*)ws;
    ws += (size_t)E * 4;
    int* seid = (int*)ws;
    ws += (size_t)E * 4;
    float* acc = (float*)ws;
    ws += (size_t)N * 64 * 4;
    float* hA = (float*)ws;
    ws += (size_t)N * 64 * 4;
    float* hB = (float*)ws;
    ws += (size_t)N * 64 * 4;
    float* dvA = (float*)ws;
    ws += (size_t)N * 64 * 4;
    float* dvB = (float*)ws;
    ws += (size_t)N * 64 * 4;

    // w12 / cbuf live in wp's region (200 KB; need 32 KB). wp is dead after
    // csr_build_k, and every writer of this region runs after csr_build_k in
    // stream order. This keeps total ws usage within the R3-proven footprint.
    float* w12_0 = (float*)wp;          // 512 floats
    float* w12_1 = w12_0 + 512;         // 4096
    float* w12_2 = w12_1 + 4096;        // 2048
    float* w12_3 = w12_2 + 2048;        // 1024
    float* cbuf = w12_3 + 1024;         // 512

    // ---- degree histogram + hierarchical-scan CSR build
    hipMemsetAsync(cnt, 0, (size_t)N * 4, stream);
    hist_k<<<(E + 255) / 256, 256, 0, stream>>>(col, cnt, E);
    blocksum_k<<<NB, 256, 0, stream>>>(cnt, bsum, N);
    scanbsum_k<<<1, 256, 0, stream>>>(bsum, NB);
    rowptr_k<<<NB, 256, 0, stream>>>(cnt, bsum, rowptr, wp, N);
    csr_build_k<<<(E + 255) / 256, 256, 0, stream>>>(row, col, wp, ssrc, seid, E);

    // ---- weight-only precompute: W12 then consts (after csr_build: reuses wp)
    gemm_w12_k<128, 64><<<8, 64, 0, stream>>>(e_w1[0], e_w2[0], w12_0);
    gemm_w12_k<128, 64><<<64, 64, 0, stream>>>(e_w1[1], e_w2[1], w12_1);
    gemm_w12_k<64, 32><<<64, 32, 0, stream>>>(e_w1[2], e_w2[2], w12_2);
    gemm_w12_k<64, 32><<<32, 32, 0, stream>>>(e_w1[3], e_w2[3], w12_3);
    consts_k<<<1, 128, 0, stream>>>(e_b1[0], e_w2[0], e_b2[0], e_b1[1], e_w2[1], e_b2[1], e_b1[2],
                                    e_w2[2], e_b2[2], e_b1[3], e_w2[3], e_b2[3], w12_1, w12_2,
                                    w12_3, cbuf);

    const int WPB = 4;  // waves per 256-thread block

    // ---- SAGE layer 0: x -> hA (64->64)
    sage_aggr64_k<<<(N + WPB - 1) / WPB, 256, 0, stream>>>(x, rowptr, ssrc, acc, N);
    sage_compute_k<64, 64><<<(N + 3) / 4, dim3(64, 4), 0, stream>>>(acc, cnt, x, s_wl[0], s_bl[0],
                                                                    s_wr[0], hA, N);
    // ---- SAGE layer 1: hA -> hB (64->64)
    sage_aggr64_k<<<(N + WPB - 1) / WPB, 256, 0, stream>>>(hA, rowptr, ssrc, acc, N);
    sage_compute_k<64, 64><<<(N + 3) / 4, dim3(64, 4), 0, stream>>>(acc, cnt, hA, s_wl[1], s_bl[1],
                                                                    s_wr[1], hB, N);
    // ---- SAGE layer 2: hB -> hA (64->32)
    sage_aggr64_k<<<(N + WPB - 1) / WPB, 256, 0, stream>>>(hB, rowptr, ssrc, acc, N);
    sage_compute_k<64, 32><<<(N + 7) / 8, dim3(32, 8), 0, stream>>>(acc, cnt, hB, s_wl[2], s_bl[2],
                                                                    s_wr[2], hA, N);
    // ---- SAGE layer 3: hA -> hB (32->32)
    sage_aggr32_k<<<(N + WPB - 1) / WPB, 256, 0, stream>>>(hA, rowptr, ssrc, acc, N);
    sage_compute_k<32, 32><<<(N + 7) / 8, dim3(32, 8), 0, stream>>>(acc, cnt, hA, s_wl[3], s_bl[3],
                                                                    s_wr[3], hB, N);

    // ---- edge conv layer 0: dis -> dvA (8->64 via W12_0)
    edge_aggr8_k<<<(N + WPB - 1) / WPB, 256, 0, stream>>>(dis, rowptr, seid, acc, N);
    edge_compute2_k<8, 64><<<(N + 3) / 4, dim3(64, 4), 0, stream>>>(acc, cnt, w12_0, cbuf + 192,
                                                                    cbuf + 192, e_b2[0], dvA, N);
    // ---- edge conv layer 1: dvA (+c1) -> dvB (64->64)
    edge_aggr_delta64_k<<<(N + WPB - 1) / WPB, 256, 0, stream>>>(dvA, cbuf + 0, rowptr, seid, acc,
                                                                 N);
    edge_compute2_k<64, 64><<<(N + 3) / 4, dim3(64, 4), 0, stream>>>(acc, cnt, w12_1, cbuf + 320,
                                                                     cbuf + 256, e_b2[1], dvB, N);
    // ---- edge conv layer 2: dvB (+c2) -> dvA (64->32)
    edge_aggr_delta64_k<<<(N + WPB - 1) / WPB, 256, 0, stream>>>(dvB, cbuf + 64, rowptr, seid, acc,
                                                                 N);
    edge_compute2_k<64, 32><<<(N + 7) / 8, dim3(32, 8), 0, stream>>>(acc, cnt, w12_2, cbuf + 416,
                                                                     cbuf + 384, e_b2[2], dvA, N);
    // ---- edge conv layer 3: dvA (+c3) -> dvB (32->32)
    edge_aggr_delta32_k<<<(N + WPB - 1) / WPB, 256, 0, stream>>>(dvA, cbuf + 128, rowptr, seid, acc,
                                                                 N);
    edge_compute2_k<32, 32><<<(N + 7) / 8, dim3(32, 8), 0, stream>>>(acc, cnt, w12_3, cbuf + 480,
                                                                     cbuf + 448, e_b2[3], dvB, N);

    // ---- final per-edge output
    final_k<<<(E + 255) / 256, 256, 0, stream>>>(hB, dvB, cbuf + 160, row, col, fcw, fcb,
                                                 (float*)d_out, E, N);
}

// Round 6
// 721.193 us; speedup vs baseline: 1.8810x; 1.2265x over previous
//
#include <hip/hip_runtime.h>

#define LRELU(v) ((v) > 0.0f ? (v) : 0.01f * (v))

// ---------------- histogram of col (in-degree) -------------------------------
__global__ void hist_k(const int* __restrict__ col, int* __restrict__ cnt, int E) {
    int e = blockIdx.x * blockDim.x + threadIdx.x;
    if (e < E) atomicAdd(&cnt[col[e]], 1);
}

// ---------------- hierarchical scan: (1) per-block sums ----------------------
__global__ void blocksum_k(const int* __restrict__ cnt, int* __restrict__ bsum, int N) {
    __shared__ int ws[4];
    int tid = threadIdx.x;
    int i = blockIdx.x * 256 + tid;
    int v = (i < N) ? cnt[i] : 0;
    for (int off = 32; off > 0; off >>= 1) v += __shfl_down(v, off);
    if ((tid & 63) == 0) ws[tid >> 6] = v;
    __syncthreads();
    if (tid == 0) bsum[blockIdx.x] = ws[0] + ws[1] + ws[2] + ws[3];
}

// ---------------- (2) exclusive scan of block sums (NB <= 256) ---------------
__global__ void scanbsum_k(int* __restrict__ bsum, int NB) {
    __shared__ int s[256];
    int tid = threadIdx.x;
    int v = (tid < NB) ? bsum[tid] : 0;
    s[tid] = v;
    __syncthreads();
    for (int off = 1; off < 256; off <<= 1) {
        int t = (tid >= off) ? s[tid - off] : 0;
        __syncthreads();
        s[tid] += t;
        __syncthreads();
    }
    if (tid < NB) bsum[tid] = s[tid] - v;  // exclusive
}

// ---------------- (3) per-block local exclusive scan + offset ----------------
__global__ void rowptr_k(const int* __restrict__ cnt, const int* __restrict__ bsum,
                         int* __restrict__ rowptr, int* __restrict__ wp, int N) {
    __shared__ int s[256];
    int tid = threadIdx.x;
    int i = blockIdx.x * 256 + tid;
    int v = (i < N) ? cnt[i] : 0;
    s[tid] = v;
    __syncthreads();
    for (int off = 1; off < 256; off <<= 1) {
        int t = (tid >= off) ? s[tid - off] : 0;
        __syncthreads();
        s[tid] += t;
        __syncthreads();
    }
    int ex = s[tid] - v + bsum[blockIdx.x];
    if (i < N) {
        rowptr[i] = ex;
        wp[i] = ex;
        if (i == N - 1) rowptr[N] = ex + v;
    }
}

// ---------------- CSR build: place (row[e], e) into slot for col[e] ----------
__global__ void csr_build_k(const int* __restrict__ row, const int* __restrict__ col,
                            int* __restrict__ wp, int* __restrict__ ssrc,
                            int* __restrict__ seid, int E) {
    int e = blockIdx.x * blockDim.x + threadIdx.x;
    if (e >= E) return;
    int pos = atomicAdd(&wp[col[e]], 1);
    ssrc[pos] = row[e];
    seid[pos] = e;
}

// ---------------- SAGE aggregate, 64-wide: wave = 4 neighbors x 16 f4-lanes --
__global__ void sage_aggr64_k(const float* __restrict__ h, const int* __restrict__ rowptr,
                              const int* __restrict__ ssrc, float* __restrict__ acc, int N) {
    int wave = (blockIdx.x * blockDim.x + threadIdx.x) >> 6;
    int lane = threadIdx.x & 63;
    if (wave >= N) return;
    int u = lane >> 4, f4 = lane & 15;
    int s = rowptr[wave], e = rowptr[wave + 1];
    float4 a = {0.f, 0.f, 0.f, 0.f};
    for (int p = s + u; p < e; p += 4) {
        const float4* hp = (const float4*)(h + (size_t)ssrc[p] * 64);
        float4 v = hp[f4];
        a.x += v.x; a.y += v.y; a.z += v.z; a.w += v.w;
    }
    a.x += __shfl_down(a.x, 32); a.y += __shfl_down(a.y, 32);
    a.z += __shfl_down(a.z, 32); a.w += __shfl_down(a.w, 32);
    a.x += __shfl_down(a.x, 16); a.y += __shfl_down(a.y, 16);
    a.z += __shfl_down(a.z, 16); a.w += __shfl_down(a.w, 16);
    if (lane < 16) ((float4*)(acc + (size_t)wave * 64))[f4] = a;
}

// ---------------- SAGE aggregate, 32-wide: wave = 8 neighbors x 8 f4-lanes ---
__global__ void sage_aggr32_k(const float* __restrict__ h, const int* __restrict__ rowptr,
                              const int* __restrict__ ssrc, float* __restrict__ acc, int N) {
    int wave = (blockIdx.x * blockDim.x + threadIdx.x) >> 6;
    int lane = threadIdx.x & 63;
    if (wave >= N) return;
    int u = lane >> 3, f4 = lane & 7;
    int s = rowptr[wave], e = rowptr[wave + 1];
    float4 a = {0.f, 0.f, 0.f, 0.f};
    for (int p = s + u; p < e; p += 8) {
        const float4* hp = (const float4*)(h + (size_t)ssrc[p] * 32);
        float4 v = hp[f4];
        a.x += v.x; a.y += v.y; a.z += v.z; a.w += v.w;
    }
    a.x += __shfl_down(a.x, 32); a.y += __shfl_down(a.y, 32);
    a.z += __shfl_down(a.z, 32); a.w += __shfl_down(a.w, 32);
    a.x += __shfl_down(a.x, 16); a.y += __shfl_down(a.y, 16);
    a.z += __shfl_down(a.z, 16); a.w += __shfl_down(a.w, 16);
    a.x += __shfl_down(a.x, 8); a.y += __shfl_down(a.y, 8);
    a.z += __shfl_down(a.z, 8); a.w += __shfl_down(a.w, 8);
    if (lane < 8) ((float4*)(acc + (size_t)wave * 32))[f4] = a;
}

// ---------------- edge conv layer 0: wave = 32 neighbors x 2 f4-lanes --------
__global__ void edge_aggr8_k(const float* __restrict__ dis, const int* __restrict__ rowptr,
                             const int* __restrict__ seid, float* __restrict__ sd, int N) {
    int wave = (blockIdx.x * blockDim.x + threadIdx.x) >> 6;
    int lane = threadIdx.x & 63;
    if (wave >= N) return;
    int u = lane >> 1, f4 = lane & 1;
    int s = rowptr[wave], e = rowptr[wave + 1];
    float4 a = {0.f, 0.f, 0.f, 0.f};
    for (int p = s + u; p < e; p += 32) {
        const float4* dp = (const float4*)(dis + (size_t)seid[p] * 8);
        float4 v = dp[f4];
        a.x += v.x; a.y += v.y; a.z += v.z; a.w += v.w;
    }
    for (int off = 32; off >= 2; off >>= 1) {
        a.x += __shfl_down(a.x, off); a.y += __shfl_down(a.y, off);
        a.z += __shfl_down(a.z, off); a.w += __shfl_down(a.w, off);
    }
    if (lane < 2) ((float4*)(sd + (size_t)wave * 8))[f4] = a;
}

// ---------------- SAGE: out = leaky(mean@wl + bl + h@wr), 4 nodes/thread -----
template <int FIN, int FOUT>
__global__ void sage_compute_k(const float* __restrict__ acc, const int* __restrict__ cnt,
                               const float* __restrict__ h, const float* __restrict__ wl,
                               const float* __restrict__ bl, const float* __restrict__ wr,
                               float* __restrict__ out, int N) {
    constexpr int ROWS = 256 / FOUT;
    constexpr int NPT = 4;
    constexpr int NPB = ROWS * NPT;
    __shared__ float swl[FIN * FOUT];
    __shared__ float swr[FIN * FOUT];
    int lin = threadIdx.y * FOUT + threadIdx.x;
    for (int idx = lin; idx < FIN * FOUT; idx += 256) {
        swl[idx] = wl[idx];
        swr[idx] = wr[idx];
    }
    __syncthreads();
    int o = threadIdx.x;
    int base = blockIdx.x * NPB + threadIdx.y * NPT;
    int idx0 = min(base + 0, N - 1), idx1 = min(base + 1, N - 1);
    int idx2 = min(base + 2, N - 1), idx3 = min(base + 3, N - 1);
    float sl[NPT] = {0.f, 0.f, 0.f, 0.f};
    float sr[NPT] = {0.f, 0.f, 0.f, 0.f};
    int ix[NPT] = {idx0, idx1, idx2, idx3};
#pragma unroll 2
    for (int f = 0; f < FIN; f += 4) {
        float w0 = swl[(f + 0) * FOUT + o], w1 = swl[(f + 1) * FOUT + o];
        float w2 = swl[(f + 2) * FOUT + o], w3 = swl[(f + 3) * FOUT + o];
        float v0 = swr[(f + 0) * FOUT + o], v1 = swr[(f + 1) * FOUT + o];
        float v2 = swr[(f + 2) * FOUT + o], v3 = swr[(f + 3) * FOUT + o];
#pragma unroll
        for (int k = 0; k < NPT; ++k) {
            float4 av = *(const float4*)(acc + (size_t)ix[k] * FIN + f);
            float4 hv = *(const float4*)(h + (size_t)ix[k] * FIN + f);
            sl[k] += av.x * w0 + av.y * w1 + av.z * w2 + av.w * w3;
            sr[k] += hv.x * v0 + hv.y * v1 + hv.z * v2 + hv.w * v3;
        }
    }
    float blo = bl[o];
#pragma unroll
    for (int k = 0; k < NPT; ++k) {
        int i = base + k;
        if (i < N) {
            float inv = 1.0f / fmaxf((float)cnt[i], 1.0f);
            float s = sl[k] * inv + sr[k] + blo;
            out[(size_t)i * FOUT + o] = LRELU(s);
        }
    }
}

// ---------------- delta scatter: sd[col[e]] += dv[e] - c, e < N (atomics) ----
template <int H, int LOG2H>
__global__ void edge_scatter_delta_k(const float* __restrict__ dv, const float* __restrict__ cvec,
                                     const int* __restrict__ col, float* __restrict__ sd, int Ne) {
    int t = blockIdx.x * blockDim.x + threadIdx.x;
    if (t >= Ne * H) return;
    int e = t >> LOG2H;
    int f = t & (H - 1);
    atomicAdd(&sd[(size_t)col[e] * H + f], dv[t] - cvec[f]);
}

// ---------------- W12 = w1 @ w2 (tiny weight-only GEMM) ----------------------
template <int H2, int HOUT>
__global__ void gemm_w12_k(const float* __restrict__ w1, const float* __restrict__ w2,
                           float* __restrict__ w12) {
    int i = blockIdx.x;   // row of w1 (HIN)
    int o = threadIdx.x;  // col of w2 (HOUT)
    float s = 0.0f;
    for (int k = 0; k < H2; ++k) s += w1[i * H2 + k] * w2[k * HOUT + o];
    w12[i * HOUT + o] = s;
}

// ---------------- collapsed edge conv, 4 nodes/thread ------------------------
// out = leaky((deg*mw2 + b1w2 + sd@W12)/(deg+1) + b2)
template <int FIN, int FOUT>
__global__ void edge_compute2_k(const float* __restrict__ sd, const int* __restrict__ cnt,
                                const float* __restrict__ w12, const float* __restrict__ mw2,
                                const float* __restrict__ b1w2, const float* __restrict__ b2,
                                float* __restrict__ out, int N) {
    constexpr int ROWS = 256 / FOUT;
    constexpr int NPT = 4;
    constexpr int NPB = ROWS * NPT;
    __shared__ float sw[FIN * FOUT];
    int lin = threadIdx.y * FOUT + threadIdx.x;
    for (int idx = lin; idx < FIN * FOUT; idx += 256) sw[idx] = w12[idx];
    __syncthreads();
    int o = threadIdx.x;
    int base = blockIdx.x * NPB + threadIdx.y * NPT;
    int ix[NPT] = {min(base + 0, N - 1), min(base + 1, N - 1), min(base + 2, N - 1),
                   min(base + 3, N - 1)};
    float s[NPT] = {0.f, 0.f, 0.f, 0.f};
#pragma unroll 2
    for (int f = 0; f < FIN; f += 4) {
        float w0 = sw[(f + 0) * FOUT + o], w1 = sw[(f + 1) * FOUT + o];
        float w2 = sw[(f + 2) * FOUT + o], w3 = sw[(f + 3) * FOUT + o];
#pragma unroll
        for (int k = 0; k < NPT; ++k) {
            float4 v = *(const float4*)(sd + (size_t)ix[k] * FIN + f);
            s[k] += v.x * w0 + v.y * w1 + v.z * w2 + v.w * w3;
        }
    }
    float mo = mw2[o], bo = b1w2[o], b2o = b2[o];
#pragma unroll
    for (int k = 0; k < NPT; ++k) {
        int i = base + k;
        if (i < N) {
            float deg = (float)cnt[i];
            float inv = 1.0f / (deg + 1.0f);
            out[(size_t)i * FOUT + o] = LRELU((s[k] + deg * mo + bo) * inv + b2o);
        }
    }
}

// ---------------- constants: c_{l+1} = leaky(b1w2_l + b2_l), mw2_l = c_l@W12_l + b1w2_l
__global__ void consts_k(const float* __restrict__ e0_b1, const float* __restrict__ e0_w2,
                         const float* __restrict__ e0_b2, const float* __restrict__ e1_b1,
                         const float* __restrict__ e1_w2, const float* __restrict__ e1_b2,
                         const float* __restrict__ e2_b1, const float* __restrict__ e2_w2,
                         const float* __restrict__ e2_b2, const float* __restrict__ e3_b1,
                         const float* __restrict__ e3_w2, const float* __restrict__ e3_b2,
                         const float* __restrict__ w12_1, const float* __restrict__ w12_2,
                         const float* __restrict__ w12_3, float* __restrict__ cbuf) {
    __shared__ float c1[64], c2[64], c3[32];
    int tid = threadIdx.x;  // 128 threads
    if (tid < 64) {
        float s = 0.0f;
        for (int k = 0; k < 128; ++k) s += e0_b1[k] * e0_w2[k * 64 + tid];
        cbuf[192 + tid] = s;  // b1w2_0 == mw2_0
        c1[tid] = LRELU(s + e0_b2[tid]);
        cbuf[tid] = c1[tid];
    }
    if (tid < 64) {
        float s = 0.0f;
        for (int k = 0; k < 128; ++k) s += e1_b1[k] * e1_w2[k * 64 + tid];
        cbuf[256 + tid] = s;  // b1w2_1
        c2[tid] = LRELU(s + e1_b2[tid]);
        cbuf[64 + tid] = c2[tid];
    }
    if (tid < 32) {
        float s = 0.0f;
        for (int k = 0; k < 64; ++k) s += e2_b1[k] * e2_w2[k * 32 + tid];
        cbuf[384 + tid] = s;  // b1w2_2
        c3[tid] = LRELU(s + e2_b2[tid]);
        cbuf[128 + tid] = c3[tid];
    }
    if (tid < 32) {
        float s = 0.0f;
        for (int k = 0; k < 64; ++k) s += e3_b1[k] * e3_w2[k * 32 + tid];
        cbuf[448 + tid] = s;                      // b1w2_3
        cbuf[160 + tid] = LRELU(s + e3_b2[tid]);  // c4
    }
    __syncthreads();
    // mw2_l = c_l @ W12_l + b1w2_l
    if (tid < 64) {
        float s = cbuf[256 + tid];
        for (int f = 0; f < 64; ++f) s += c1[f] * w12_1[f * 64 + tid];
        cbuf[320 + tid] = s;  // mw2_1
    }
    if (tid < 32) {
        float s = cbuf[384 + tid];
        for (int f = 0; f < 64; ++f) s += c2[f] * w12_2[f * 32 + tid];
        cbuf[416 + tid] = s;  // mw2_2
    }
    if (tid < 32) {
        float s = cbuf[448 + tid];
        for (int f = 0; f < 32; ++f) s += c3[f] * w12_3[f * 32 + tid];
        cbuf[480 + tid] = s;  // mw2_3
    }
}

// ---------------- final: out[e] = dot(h[row]*h[col], fcw[0:32]) + dot(d[e], fcw[32:64]) + fcb
__global__ void final_k(const float* __restrict__ h3, const float* __restrict__ dv3,
                        const float* __restrict__ c4, const int* __restrict__ row,
                        const int* __restrict__ col, const float* __restrict__ fcw,
                        const float* __restrict__ fcb, float* __restrict__ out, int E, int N) {
    __shared__ float sw[64];
    __shared__ float sc4[32];
    int tid = threadIdx.x;
    if (tid < 64) sw[tid] = fcw[tid];
    if (tid < 32) sc4[tid] = c4[tid];
    __syncthreads();
    int e = blockIdx.x * blockDim.x + tid;
    if (e >= E) return;
    int r = row[e], c = col[e];
    const float4* hr = (const float4*)(h3 + (size_t)r * 32);
    const float4* hc = (const float4*)(h3 + (size_t)c * 32);
    float s = fcb[0];
#pragma unroll
    for (int q = 0; q < 8; ++q) {
        float4 a = hr[q], b = hc[q];
        s += a.x * b.x * sw[q * 4 + 0] + a.y * b.y * sw[q * 4 + 1] + a.z * b.z * sw[q * 4 + 2] +
             a.w * b.w * sw[q * 4 + 3];
    }
    if (e < N) {
        const float4* dp = (const float4*)(dv3 + (size_t)e * 32);
#pragma unroll
        for (int q = 0; q < 8; ++q) {
            float4 d = dp[q];
            s += d.x * sw[32 + q * 4 + 0] + d.y * sw[32 + q * 4 + 1] + d.z * sw[32 + q * 4 + 2] +
                 d.w * sw[32 + q * 4 + 3];
        }
    } else {
#pragma unroll
        for (int k = 0; k < 32; ++k) s += sc4[k] * sw[32 + k];
    }
    out[e] = s;
}

extern "C" void kernel_launch(void* const* d_in, const int* in_sizes, int n_in, void* d_out,
                              int out_size, void* d_ws, size_t ws_size, hipStream_t stream) {
    const float* x = (const float*)d_in[0];
    const float* dis = (const float*)d_in[1];
    const int* ei = (const int*)d_in[2];
    const float* s_wl[4] = {(const float*)d_in[3], (const float*)d_in[6], (const float*)d_in[9],
                            (const float*)d_in[12]};
    const float* s_bl[4] = {(const float*)d_in[4], (const float*)d_in[7], (const float*)d_in[10],
                            (const float*)d_in[13]};
    const float* s_wr[4] = {(const float*)d_in[5], (const float*)d_in[8], (const float*)d_in[11],
                            (const float*)d_in[14]};
    const float* e_w1[4] = {(const float*)d_in[15], (const float*)d_in[19], (const float*)d_in[23],
                            (const float*)d_in[27]};
    const float* e_b1[4] = {(const float*)d_in[16], (const float*)d_in[20], (const float*)d_in[24],
                            (const float*)d_in[28]};
    const float* e_w2[4] = {(const float*)d_in[17], (const float*)d_in[21], (const float*)d_in[25],
                            (const float*)d_in[29]};
    const float* e_b2[4] = {(const float*)d_in[18], (const float*)d_in[22], (const float*)d_in[26],
                            (const float*)d_in[30]};
    const float* fcw = (const float*)d_in[31];
    const float* fcb = (const float*)d_in[32];

    const int N = in_sizes[0] / 64;
    const int E = in_sizes[1] / 8;
    const int* row = ei;
    const int* col = ei + E;
    const int NB = (N + 255) / 256;

    // ---- workspace carve (each region 256B-aligned; total <= proven footprint)
    auto au = [](size_t v) { return (v + 255) & ~(size_t)255; };
    char* p = (char*)d_ws;
    int* cnt = (int*)p;      p += au((size_t)N * 4);
    int* rowptr = (int*)p;   p += au((size_t)(N + 1) * 4);
    int* wp = (int*)p;       p += au((size_t)N * 4);
    int* bsum = (int*)p;     p += au((size_t)256 * 4);
    int* ssrc = (int*)p;     p += au((size_t)E * 4);
    int* seid = (int*)p;     p += au((size_t)E * 4);
    float* acc = (float*)p;  p += au((size_t)N * 64 * 4);
    float* hA = (float*)p;   p += au((size_t)N * 64 * 4);
    float* hB = (float*)p;   p += au((size_t)N * 64 * 4);
    float* dvA = (float*)p;  p += au((size_t)N * 64 * 4);
    float* dvB = (float*)p;  p += au((size_t)N * 64 * 4);

    // w12 / cbuf live inside wp's region (200 KB; need 32 KB). wp is dead after
    // csr_build_k and all writers of these run after it in stream order.
    float* w12_0 = (float*)wp;   // 512 floats
    float* w12_1 = w12_0 + 512;  // 4096
    float* w12_2 = w12_1 + 4096; // 2048
    float* w12_3 = w12_2 + 2048; // 1024
    float* cbuf = w12_3 + 1024;  // 512

    // ---- degree histogram + hierarchical-scan CSR build
    hipMemsetAsync(cnt, 0, (size_t)N * 4, stream);
    hist_k<<<(E + 255) / 256, 256, 0, stream>>>(col, cnt, E);
    blocksum_k<<<NB, 256, 0, stream>>>(cnt, bsum, N);
    scanbsum_k<<<1, 256, 0, stream>>>(bsum, NB);
    rowptr_k<<<NB, 256, 0, stream>>>(cnt, bsum, rowptr, wp, N);
    csr_build_k<<<(E + 255) / 256, 256, 0, stream>>>(row, col, wp, ssrc, seid, E);

    // ---- weight-only precompute: W12 then consts (after csr_build: reuses wp)
    gemm_w12_k<128, 64><<<8, 64, 0, stream>>>(e_w1[0], e_w2[0], w12_0);
    gemm_w12_k<128, 64><<<64, 64, 0, stream>>>(e_w1[1], e_w2[1], w12_1);
    gemm_w12_k<64, 32><<<64, 32, 0, stream>>>(e_w1[2], e_w2[2], w12_2);
    gemm_w12_k<64, 32><<<32, 32, 0, stream>>>(e_w1[3], e_w2[3], w12_3);
    consts_k<<<1, 128, 0, stream>>>(e_b1[0], e_w2[0], e_b2[0], e_b1[1], e_w2[1], e_b2[1], e_b1[2],
                                    e_w2[2], e_b2[2], e_b1[3], e_w2[3], e_b2[3], w12_1, w12_2,
                                    w12_3, cbuf);

    const int WPB = 4;  // waves per 256-thread block in aggr kernels

    // ---- SAGE layer 0: x -> hA (64->64)
    sage_aggr64_k<<<(N + WPB - 1) / WPB, 256, 0, stream>>>(x, rowptr, ssrc, acc, N);
    sage_compute_k<64, 64><<<(N + 15) / 16, dim3(64, 4), 0, stream>>>(acc, cnt, x, s_wl[0],
                                                                      s_bl[0], s_wr[0], hA, N);
    // ---- SAGE layer 1: hA -> hB (64->64)
    sage_aggr64_k<<<(N + WPB - 1) / WPB, 256, 0, stream>>>(hA, rowptr, ssrc, acc, N);
    sage_compute_k<64, 64><<<(N + 15) / 16, dim3(64, 4), 0, stream>>>(acc, cnt, hA, s_wl[1],
                                                                      s_bl[1], s_wr[1], hB, N);
    // ---- SAGE layer 2: hB -> hA (64->32)
    sage_aggr64_k<<<(N + WPB - 1) / WPB, 256, 0, stream>>>(hB, rowptr, ssrc, acc, N);
    sage_compute_k<64, 32><<<(N + 31) / 32, dim3(32, 8), 0, stream>>>(acc, cnt, hB, s_wl[2],
                                                                      s_bl[2], s_wr[2], hA, N);
    // ---- SAGE layer 3: hA -> hB (32->32)
    sage_aggr32_k<<<(N + WPB - 1) / WPB, 256, 0, stream>>>(hA, rowptr, ssrc, acc, N);
    sage_compute_k<32, 32><<<(N + 31) / 32, dim3(32, 8), 0, stream>>>(acc, cnt, hA, s_wl[3],
                                                                      s_bl[3], s_wr[3], hB, N);

    // ---- edge conv layer 0: dis -> dvA (8->64 via W12_0)
    edge_aggr8_k<<<(N + WPB - 1) / WPB, 256, 0, stream>>>(dis, rowptr, seid, acc, N);
    edge_compute2_k<8, 64><<<(N + 15) / 16, dim3(64, 4), 0, stream>>>(acc, cnt, w12_0, cbuf + 192,
                                                                      cbuf + 192, e_b2[0], dvA, N);
    // ---- edge conv layer 1: dvA (+c1) -> dvB (64->64)
    hipMemsetAsync(acc, 0, (size_t)N * 64 * 4, stream);
    edge_scatter_delta_k<64, 6><<<(N * 64 + 255) / 256, 256, 0, stream>>>(dvA, cbuf + 0, col, acc,
                                                                          N);
    edge_compute2_k<64, 64><<<(N + 15) / 16, dim3(64, 4), 0, stream>>>(acc, cnt, w12_1, cbuf + 320,
                                                                       cbuf + 256, e_b2[1], dvB, N);
    // ---- edge conv layer 2: dvB (+c2) -> dvA (64->32)
    hipMemsetAsync(acc, 0, (size_t)N * 64 * 4, stream);
    edge_scatter_delta_k<64, 6><<<(N * 64 + 255) / 256, 256, 0, stream>>>(dvB, cbuf + 64, col, acc,
                                                                          N);
    edge_compute2_k<64, 32><<<(N + 31) / 32, dim3(32, 8), 0, stream>>>(acc, cnt, w12_2, cbuf + 416,
                                                                       cbuf + 384, e_b2[2], dvA, N);
    // ---- edge conv layer 3: dvA (+c3) -> dvB (32->32)
    hipMemsetAsync(acc, 0, (size_t)N * 32 * 4, stream);
    edge_scatter_delta_k<32, 5><<<(N * 32 + 255) / 256, 256, 0, stream>>>(dvA, cbuf + 128, col, acc,
                                                                          N);
    edge_compute2_k<32, 32><<<(N + 31) / 32, dim3(32, 8), 0, stream>>>(acc, cnt, w12_3, cbuf + 480,
                                                                       cbuf + 448, e_b2[3], dvB, N);

    // ---- final per-edge output
    final_k<<<(E + 255) / 256, 256, 0, stream>>>(hB, dvB, cbuf + 160, row, col, fcw, fcb,
                                                 (float*)d_out, E, N);
}

// Round 7
// 622.881 us; speedup vs baseline: 2.1778x; 1.1578x over previous
//
#include <hip/hip_runtime.h>

#define LRELU(v) ((v) > 0.0f ? (v) : 0.01f * (v))

// ---------------- histogram of col (in-degree) -------------------------------
__global__ void hist_k(const int* __restrict__ col, int* __restrict__ cnt, int E) {
    int e = blockIdx.x * blockDim.x + threadIdx.x;
    if (e < E) atomicAdd(&cnt[col[e]], 1);
}

// ---------------- hierarchical scan: (1) per-block sums ----------------------
__global__ void blocksum_k(const int* __restrict__ cnt, int* __restrict__ bsum, int N) {
    __shared__ int ws[4];
    int tid = threadIdx.x;
    int i = blockIdx.x * 256 + tid;
    int v = (i < N) ? cnt[i] : 0;
    for (int off = 32; off > 0; off >>= 1) v += __shfl_down(v, off);
    if ((tid & 63) == 0) ws[tid >> 6] = v;
    __syncthreads();
    if (tid == 0) bsum[blockIdx.x] = ws[0] + ws[1] + ws[2] + ws[3];
}

// ---------------- (2) exclusive scan of block sums (NB <= 256) ---------------
__global__ void scanbsum_k(int* __restrict__ bsum, int NB) {
    __shared__ int s[256];
    int tid = threadIdx.x;
    int v = (tid < NB) ? bsum[tid] : 0;
    s[tid] = v;
    __syncthreads();
    for (int off = 1; off < 256; off <<= 1) {
        int t = (tid >= off) ? s[tid - off] : 0;
        __syncthreads();
        s[tid] += t;
        __syncthreads();
    }
    if (tid < NB) bsum[tid] = s[tid] - v;  // exclusive
}

// ---------------- (3) per-block local exclusive scan + offset ----------------
__global__ void rowptr_k(const int* __restrict__ cnt, const int* __restrict__ bsum,
                         int* __restrict__ rowptr, int* __restrict__ wp, int N) {
    __shared__ int s[256];
    int tid = threadIdx.x;
    int i = blockIdx.x * 256 + tid;
    int v = (i < N) ? cnt[i] : 0;
    s[tid] = v;
    __syncthreads();
    for (int off = 1; off < 256; off <<= 1) {
        int t = (tid >= off) ? s[tid - off] : 0;
        __syncthreads();
        s[tid] += t;
        __syncthreads();
    }
    int ex = s[tid] - v + bsum[blockIdx.x];
    if (i < N) {
        rowptr[i] = ex;
        wp[i] = ex;
        if (i == N - 1) rowptr[N] = ex + v;
    }
}

// ---------------- CSR build: place (row[e], e) into slot for col[e] ----------
__global__ void csr_build_k(const int* __restrict__ row, const int* __restrict__ col,
                            int* __restrict__ wp, int* __restrict__ ssrc,
                            int* __restrict__ seid, int E) {
    int e = blockIdx.x * blockDim.x + threadIdx.x;
    if (e >= E) return;
    int pos = atomicAdd(&wp[col[e]], 1);
    ssrc[pos] = row[e];
    seid[pos] = e;
}

// ---------------- dual GEMM: hl = h@wl, hr = h@wr + bl -----------------------
// block dim3(2*FOUT/4, 256/(2*FOUT/4)); 4 nodes x 4 outs per thread.
template <int FIN, int FOUT>
__global__ void gemm2_k(const float* __restrict__ h, const float* __restrict__ wl,
                        const float* __restrict__ wr, const float* __restrict__ bl,
                        float* __restrict__ hl, float* __restrict__ hr, int N) {
    constexpr int XT = (2 * FOUT) / 4;
    constexpr int YT = 256 / XT;
    constexpr int NPT = 4;
    constexpr int NPB = YT * NPT;
    __shared__ float sw[FIN * 2 * FOUT];
    int lin = threadIdx.y * XT + threadIdx.x;
    for (int idx = lin; idx < FIN * FOUT; idx += 256) {
        int f = idx / FOUT, o = idx % FOUT;
        sw[f * 2 * FOUT + o] = wl[idx];
        sw[f * 2 * FOUT + FOUT + o] = wr[idx];
    }
    __syncthreads();
    int og = threadIdx.x * 4;
    int base = blockIdx.x * NPB + threadIdx.y * NPT;
    int ix[NPT] = {min(base + 0, N - 1), min(base + 1, N - 1), min(base + 2, N - 1),
                   min(base + 3, N - 1)};
    float4 s[NPT] = {{0.f, 0.f, 0.f, 0.f}, {0.f, 0.f, 0.f, 0.f}, {0.f, 0.f, 0.f, 0.f},
                     {0.f, 0.f, 0.f, 0.f}};
#pragma unroll 2
    for (int f = 0; f < FIN; f += 4) {
        float4 w0 = *(const float4*)&sw[(f + 0) * 2 * FOUT + og];
        float4 w1 = *(const float4*)&sw[(f + 1) * 2 * FOUT + og];
        float4 w2 = *(const float4*)&sw[(f + 2) * 2 * FOUT + og];
        float4 w3 = *(const float4*)&sw[(f + 3) * 2 * FOUT + og];
#pragma unroll
        for (int k = 0; k < NPT; ++k) {
            float4 v = *(const float4*)(h + (size_t)ix[k] * FIN + f);
            s[k].x += v.x * w0.x + v.y * w1.x + v.z * w2.x + v.w * w3.x;
            s[k].y += v.x * w0.y + v.y * w1.y + v.z * w2.y + v.w * w3.y;
            s[k].z += v.x * w0.z + v.y * w1.z + v.z * w2.z + v.w * w3.z;
            s[k].w += v.x * w0.w + v.y * w1.w + v.z * w2.w + v.w * w3.w;
        }
    }
    bool isR = og >= FOUT;
    int oo = isR ? og - FOUT : og;
    float4 bias = {0.f, 0.f, 0.f, 0.f};
    if (isR) bias = *(const float4*)&bl[oo];
    float* dst = isR ? hr : hl;
#pragma unroll
    for (int k = 0; k < NPT; ++k) {
        int i = base + k;
        if (i < N) {
            float4 r = {s[k].x + bias.x, s[k].y + bias.y, s[k].z + bias.z, s[k].w + bias.w};
            *(float4*)(dst + (size_t)i * FOUT + oo) = r;
        }
    }
}

// ---------------- fused SAGE aggregate+epilogue, 64-wide ---------------------
// out = leaky(gather_sum(hl)/max(deg,1) + hr)
__global__ void aggr_fused64_k(const float* __restrict__ hl, const float* __restrict__ hr,
                               const int* __restrict__ rowptr, const int* __restrict__ ssrc,
                               float* __restrict__ out, int N) {
    int wave = (blockIdx.x * blockDim.x + threadIdx.x) >> 6;
    int lane = threadIdx.x & 63;
    if (wave >= N) return;
    int u = lane >> 4, f4 = lane & 15;
    int s = rowptr[wave], e = rowptr[wave + 1];
    float4 a = {0.f, 0.f, 0.f, 0.f};
    for (int p = s + u; p < e; p += 4) {
        const float4* hp = (const float4*)(hl + (size_t)ssrc[p] * 64);
        float4 v = hp[f4];
        a.x += v.x; a.y += v.y; a.z += v.z; a.w += v.w;
    }
    a.x += __shfl_down(a.x, 32); a.y += __shfl_down(a.y, 32);
    a.z += __shfl_down(a.z, 32); a.w += __shfl_down(a.w, 32);
    a.x += __shfl_down(a.x, 16); a.y += __shfl_down(a.y, 16);
    a.z += __shfl_down(a.z, 16); a.w += __shfl_down(a.w, 16);
    if (lane < 16) {
        float inv = 1.0f / fmaxf((float)(e - s), 1.0f);
        float4 r = ((const float4*)(hr + (size_t)wave * 64))[f4];
        float4 o;
        o.x = LRELU(a.x * inv + r.x);
        o.y = LRELU(a.y * inv + r.y);
        o.z = LRELU(a.z * inv + r.z);
        o.w = LRELU(a.w * inv + r.w);
        ((float4*)(out + (size_t)wave * 64))[f4] = o;
    }
}

// ---------------- fused SAGE aggregate+epilogue, 32-wide ---------------------
__global__ void aggr_fused32_k(const float* __restrict__ hl, const float* __restrict__ hr,
                               const int* __restrict__ rowptr, const int* __restrict__ ssrc,
                               float* __restrict__ out, int N) {
    int wave = (blockIdx.x * blockDim.x + threadIdx.x) >> 6;
    int lane = threadIdx.x & 63;
    if (wave >= N) return;
    int u = lane >> 3, f4 = lane & 7;
    int s = rowptr[wave], e = rowptr[wave + 1];
    float4 a = {0.f, 0.f, 0.f, 0.f};
    for (int p = s + u; p < e; p += 8) {
        const float4* hp = (const float4*)(hl + (size_t)ssrc[p] * 32);
        float4 v = hp[f4];
        a.x += v.x; a.y += v.y; a.z += v.z; a.w += v.w;
    }
    a.x += __shfl_down(a.x, 32); a.y += __shfl_down(a.y, 32);
    a.z += __shfl_down(a.z, 32); a.w += __shfl_down(a.w, 32);
    a.x += __shfl_down(a.x, 16); a.y += __shfl_down(a.y, 16);
    a.z += __shfl_down(a.z, 16); a.w += __shfl_down(a.w, 16);
    a.x += __shfl_down(a.x, 8); a.y += __shfl_down(a.y, 8);
    a.z += __shfl_down(a.z, 8); a.w += __shfl_down(a.w, 8);
    if (lane < 8) {
        float inv = 1.0f / fmaxf((float)(e - s), 1.0f);
        float4 r = ((const float4*)(hr + (size_t)wave * 32))[f4];
        float4 o;
        o.x = LRELU(a.x * inv + r.x);
        o.y = LRELU(a.y * inv + r.y);
        o.z = LRELU(a.z * inv + r.z);
        o.w = LRELU(a.w * inv + r.w);
        ((float4*)(out + (size_t)wave * 32))[f4] = o;
    }
}

// ---------------- edge conv layer 0: wave = 32 neighbors x 2 f4-lanes --------
__global__ void edge_aggr8_k(const float* __restrict__ dis, const int* __restrict__ rowptr,
                             const int* __restrict__ seid, float* __restrict__ sd, int N) {
    int wave = (blockIdx.x * blockDim.x + threadIdx.x) >> 6;
    int lane = threadIdx.x & 63;
    if (wave >= N) return;
    int u = lane >> 1, f4 = lane & 1;
    int s = rowptr[wave], e = rowptr[wave + 1];
    float4 a = {0.f, 0.f, 0.f, 0.f};
    for (int p = s + u; p < e; p += 32) {
        const float4* dp = (const float4*)(dis + (size_t)seid[p] * 8);
        float4 v = dp[f4];
        a.x += v.x; a.y += v.y; a.z += v.z; a.w += v.w;
    }
    for (int off = 32; off >= 2; off >>= 1) {
        a.x += __shfl_down(a.x, off); a.y += __shfl_down(a.y, off);
        a.z += __shfl_down(a.z, off); a.w += __shfl_down(a.w, off);
    }
    if (lane < 2) ((float4*)(sd + (size_t)wave * 8))[f4] = a;
}

// ---------------- delta scatter: sd[col[e]] += dv[e] - c, e < N (atomics) ----
template <int H, int LOG2H>
__global__ void edge_scatter_delta_k(const float* __restrict__ dv, const float* __restrict__ cvec,
                                     const int* __restrict__ col, float* __restrict__ sd, int Ne) {
    int t = blockIdx.x * blockDim.x + threadIdx.x;
    if (t >= Ne * H) return;
    int e = t >> LOG2H;
    int f = t & (H - 1);
    atomicAdd(&sd[(size_t)col[e] * H + f], dv[t] - cvec[f]);
}

// ---------------- W12 = w1 @ w2 (tiny weight-only GEMM) ----------------------
template <int H2, int HOUT>
__global__ void gemm_w12_k(const float* __restrict__ w1, const float* __restrict__ w2,
                           float* __restrict__ w12) {
    int i = blockIdx.x;   // row of w1 (HIN)
    int o = threadIdx.x;  // col of w2 (HOUT)
    float s = 0.0f;
    for (int k = 0; k < H2; ++k) s += w1[i * H2 + k] * w2[k * HOUT + o];
    w12[i * HOUT + o] = s;
}

// ---------------- collapsed edge conv, 4 nodes/thread ------------------------
// out = leaky((deg*mw2 + b1w2 + sd@W12)/(deg+1) + b2)
template <int FIN, int FOUT>
__global__ void edge_compute2_k(const float* __restrict__ sd, const int* __restrict__ cnt,
                                const float* __restrict__ w12, const float* __restrict__ mw2,
                                const float* __restrict__ b1w2, const float* __restrict__ b2,
                                float* __restrict__ out, int N) {
    constexpr int ROWS = 256 / FOUT;
    constexpr int NPT = 4;
    constexpr int NPB = ROWS * NPT;
    __shared__ float sw[FIN * FOUT];
    int lin = threadIdx.y * FOUT + threadIdx.x;
    for (int idx = lin; idx < FIN * FOUT; idx += 256) sw[idx] = w12[idx];
    __syncthreads();
    int o = threadIdx.x;
    int base = blockIdx.x * NPB + threadIdx.y * NPT;
    int ix[NPT] = {min(base + 0, N - 1), min(base + 1, N - 1), min(base + 2, N - 1),
                   min(base + 3, N - 1)};
    float s[NPT] = {0.f, 0.f, 0.f, 0.f};
#pragma unroll 2
    for (int f = 0; f < FIN; f += 4) {
        float w0 = sw[(f + 0) * FOUT + o], w1 = sw[(f + 1) * FOUT + o];
        float w2 = sw[(f + 2) * FOUT + o], w3 = sw[(f + 3) * FOUT + o];
#pragma unroll
        for (int k = 0; k < NPT; ++k) {
            float4 v = *(const float4*)(sd + (size_t)ix[k] * FIN + f);
            s[k] += v.x * w0 + v.y * w1 + v.z * w2 + v.w * w3;
        }
    }
    float mo = mw2[o], bo = b1w2[o], b2o = b2[o];
#pragma unroll
    for (int k = 0; k < NPT; ++k) {
        int i = base + k;
        if (i < N) {
            float deg = (float)cnt[i];
            float inv = 1.0f / (deg + 1.0f);
            out[(size_t)i * FOUT + o] = LRELU((s[k] + deg * mo + bo) * inv + b2o);
        }
    }
}

// ---------------- constants: c_{l+1} = leaky(b1w2_l + b2_l), mw2_l = c_l@W12_l + b1w2_l
__global__ void consts_k(const float* __restrict__ e0_b1, const float* __restrict__ e0_w2,
                         const float* __restrict__ e0_b2, const float* __restrict__ e1_b1,
                         const float* __restrict__ e1_w2, const float* __restrict__ e1_b2,
                         const float* __restrict__ e2_b1, const float* __restrict__ e2_w2,
                         const float* __restrict__ e2_b2, const float* __restrict__ e3_b1,
                         const float* __restrict__ e3_w2, const float* __restrict__ e3_b2,
                         const float* __restrict__ w12_1, const float* __restrict__ w12_2,
                         const float* __restrict__ w12_3, float* __restrict__ cbuf) {
    __shared__ float c1[64], c2[64], c3[32];
    int tid = threadIdx.x;  // 128 threads
    if (tid < 64) {
        float s = 0.0f;
        for (int k = 0; k < 128; ++k) s += e0_b1[k] * e0_w2[k * 64 + tid];
        cbuf[192 + tid] = s;  // b1w2_0 == mw2_0
        c1[tid] = LRELU(s + e0_b2[tid]);
        cbuf[tid] = c1[tid];
    }
    if (tid < 64) {
        float s = 0.0f;
        for (int k = 0; k < 128; ++k) s += e1_b1[k] * e1_w2[k * 64 + tid];
        cbuf[256 + tid] = s;  // b1w2_1
        c2[tid] = LRELU(s + e1_b2[tid]);
        cbuf[64 + tid] = c2[tid];
    }
    if (tid < 32) {
        float s = 0.0f;
        for (int k = 0; k < 64; ++k) s += e2_b1[k] * e2_w2[k * 32 + tid];
        cbuf[384 + tid] = s;  // b1w2_2
        c3[tid] = LRELU(s + e2_b2[tid]);
        cbuf[128 + tid] = c3[tid];
    }
    if (tid < 32) {
        float s = 0.0f;
        for (int k = 0; k < 64; ++k) s += e3_b1[k] * e3_w2[k * 32 + tid];
        cbuf[448 + tid] = s;                      // b1w2_3
        cbuf[160 + tid] = LRELU(s + e3_b2[tid]);  // c4
    }
    __syncthreads();
    // mw2_l = c_l @ W12_l + b1w2_l
    if (tid < 64) {
        float s = cbuf[256 + tid];
        for (int f = 0; f < 64; ++f) s += c1[f] * w12_1[f * 64 + tid];
        cbuf[320 + tid] = s;  // mw2_1
    }
    if (tid < 32) {
        float s = cbuf[384 + tid];
        for (int f = 0; f < 64; ++f) s += c2[f] * w12_2[f * 32 + tid];
        cbuf[416 + tid] = s;  // mw2_2
    }
    if (tid < 32) {
        float s = cbuf[448 + tid];
        for (int f = 0; f < 32; ++f) s += c3[f] * w12_3[f * 32 + tid];
        cbuf[480 + tid] = s;  // mw2_3
    }
}

// ---------------- final: out[e] = dot(h[row]*h[col], fcw[0:32]) + dot(d[e], fcw[32:64]) + fcb
__global__ void final_k(const float* __restrict__ h3, const float* __restrict__ dv3,
                        const float* __restrict__ c4, const int* __restrict__ row,
                        const int* __restrict__ col, const float* __restrict__ fcw,
                        const float* __restrict__ fcb, float* __restrict__ out, int E, int N) {
    __shared__ float sw[64];
    __shared__ float sc4[32];
    int tid = threadIdx.x;
    if (tid < 64) sw[tid] = fcw[tid];
    if (tid < 32) sc4[tid] = c4[tid];
    __syncthreads();
    int e = blockIdx.x * blockDim.x + tid;
    if (e >= E) return;
    int r = row[e], c = col[e];
    const float4* hr = (const float4*)(h3 + (size_t)r * 32);
    const float4* hc = (const float4*)(h3 + (size_t)c * 32);
    float s = fcb[0];
#pragma unroll
    for (int q = 0; q < 8; ++q) {
        float4 a = hr[q], b = hc[q];
        s += a.x * b.x * sw[q * 4 + 0] + a.y * b.y * sw[q * 4 + 1] + a.z * b.z * sw[q * 4 + 2] +
             a.w * b.w * sw[q * 4 + 3];
    }
    if (e < N) {
        const float4* dp = (const float4*)(dv3 + (size_t)e * 32);
#pragma unroll
        for (int q = 0; q < 8; ++q) {
            float4 d = dp[q];
            s += d.x * sw[32 + q * 4 + 0] + d.y * sw[32 + q * 4 + 1] + d.z * sw[32 + q * 4 + 2] +
                 d.w * sw[32 + q * 4 + 3];
        }
    } else {
#pragma unroll
        for (int k = 0; k < 32; ++k) s += sc4[k] * sw[32 + k];
    }
    out[e] = s;
}

extern "C" void kernel_launch(void* const* d_in, const int* in_sizes, int n_in, void* d_out,
                              int out_size, void* d_ws, size_t ws_size, hipStream_t stream) {
    const float* x = (const float*)d_in[0];
    const float* dis = (const float*)d_in[1];
    const int* ei = (const int*)d_in[2];
    const float* s_wl[4] = {(const float*)d_in[3], (const float*)d_in[6], (const float*)d_in[9],
                            (const float*)d_in[12]};
    const float* s_bl[4] = {(const float*)d_in[4], (const float*)d_in[7], (const float*)d_in[10],
                            (const float*)d_in[13]};
    const float* s_wr[4] = {(const float*)d_in[5], (const float*)d_in[8], (const float*)d_in[11],
                            (const float*)d_in[14]};
    const float* e_w1[4] = {(const float*)d_in[15], (const float*)d_in[19], (const float*)d_in[23],
                            (const float*)d_in[27]};
    const float* e_b1[4] = {(const float*)d_in[16], (const float*)d_in[20], (const float*)d_in[24],
                            (const float*)d_in[28]};
    const float* e_w2[4] = {(const float*)d_in[17], (const float*)d_in[21], (const float*)d_in[25],
                            (const float*)d_in[29]};
    const float* e_b2[4] = {(const float*)d_in[18], (const float*)d_in[22], (const float*)d_in[26],
                            (const float*)d_in[30]};
    const float* fcw = (const float*)d_in[31];
    const float* fcb = (const float*)d_in[32];

    const int N = in_sizes[0] / 64;
    const int E = in_sizes[1] / 8;
    const int* row = ei;
    const int* col = ei + E;
    const int NB = (N + 255) / 256;

    // ---- workspace carve (each region 256B-aligned; total <= proven footprint)
    auto au = [](size_t v) { return (v + 255) & ~(size_t)255; };
    char* p = (char*)d_ws;
    int* cnt = (int*)p;      p += au((size_t)N * 4);
    int* rowptr = (int*)p;   p += au((size_t)(N + 1) * 4);
    int* wp = (int*)p;       p += au((size_t)N * 4);
    int* bsum = (int*)p;     p += au((size_t)256 * 4);
    int* ssrc = (int*)p;     p += au((size_t)E * 4);
    int* seid = (int*)p;     p += au((size_t)E * 4);
    float* acc = (float*)p;  p += au((size_t)N * 64 * 4);
    float* hA = (float*)p;   p += au((size_t)N * 64 * 4);
    float* hB = (float*)p;   p += au((size_t)N * 64 * 4);
    float* dvA = (float*)p;  p += au((size_t)N * 64 * 4);
    float* dvB = (float*)p;  p += au((size_t)N * 64 * 4);

    // w12 / cbuf live inside wp's region (200 KB; need 32 KB). wp is dead after
    // csr_build_k and all writers of these run after it in stream order.
    float* w12_0 = (float*)wp;   // 512 floats
    float* w12_1 = w12_0 + 512;  // 4096
    float* w12_2 = w12_1 + 4096; // 2048
    float* w12_3 = w12_2 + 2048; // 1024
    float* cbuf = w12_3 + 1024;  // 512

    // ---- degree histogram + hierarchical-scan CSR build
    hipMemsetAsync(cnt, 0, (size_t)N * 4, stream);
    hist_k<<<(E + 255) / 256, 256, 0, stream>>>(col, cnt, E);
    blocksum_k<<<NB, 256, 0, stream>>>(cnt, bsum, N);
    scanbsum_k<<<1, 256, 0, stream>>>(bsum, NB);
    rowptr_k<<<NB, 256, 0, stream>>>(cnt, bsum, rowptr, wp, N);
    csr_build_k<<<(E + 255) / 256, 256, 0, stream>>>(row, col, wp, ssrc, seid, E);

    // ---- weight-only precompute: W12 then consts (after csr_build: reuses wp)
    gemm_w12_k<128, 64><<<8, 64, 0, stream>>>(e_w1[0], e_w2[0], w12_0);
    gemm_w12_k<128, 64><<<64, 64, 0, stream>>>(e_w1[1], e_w2[1], w12_1);
    gemm_w12_k<64, 32><<<64, 32, 0, stream>>>(e_w1[2], e_w2[2], w12_2);
    gemm_w12_k<64, 32><<<32, 32, 0, stream>>>(e_w1[3], e_w2[3], w12_3);
    consts_k<<<1, 128, 0, stream>>>(e_b1[0], e_w2[0], e_b2[0], e_b1[1], e_w2[1], e_b2[1], e_b1[2],
                                    e_w2[2], e_b2[2], e_b1[3], e_w2[3], e_b2[3], w12_1, w12_2,
                                    w12_3, cbuf);

    const int WPB = 4;  // waves per 256-thread block in aggr kernels

    // ---- SAGE layer 0: x -> hA (64->64)
    gemm2_k<64, 64><<<(N + 31) / 32, dim3(32, 8), 0, stream>>>(x, s_wl[0], s_wr[0], s_bl[0], acc,
                                                               dvB, N);
    aggr_fused64_k<<<(N + WPB - 1) / WPB, 256, 0, stream>>>(acc, dvB, rowptr, ssrc, hA, N);
    // ---- SAGE layer 1: hA -> hB (64->64)
    gemm2_k<64, 64><<<(N + 31) / 32, dim3(32, 8), 0, stream>>>(hA, s_wl[1], s_wr[1], s_bl[1], acc,
                                                               dvB, N);
    aggr_fused64_k<<<(N + WPB - 1) / WPB, 256, 0, stream>>>(acc, dvB, rowptr, ssrc, hB, N);
    // ---- SAGE layer 2: hB -> hA (64->32)
    gemm2_k<64, 32><<<(N + 63) / 64, dim3(16, 16), 0, stream>>>(hB, s_wl[2], s_wr[2], s_bl[2], acc,
                                                                dvB, N);
    aggr_fused32_k<<<(N + WPB - 1) / WPB, 256, 0, stream>>>(acc, dvB, rowptr, ssrc, hA, N);
    // ---- SAGE layer 3: hA -> hB (32->32)
    gemm2_k<32, 32><<<(N + 63) / 64, dim3(16, 16), 0, stream>>>(hA, s_wl[3], s_wr[3], s_bl[3], acc,
                                                                dvB, N);
    aggr_fused32_k<<<(N + WPB - 1) / WPB, 256, 0, stream>>>(acc, dvB, rowptr, ssrc, hB, N);

    // ---- edge conv layer 0: dis -> dvA (8->64 via W12_0)
    edge_aggr8_k<<<(N + WPB - 1) / WPB, 256, 0, stream>>>(dis, rowptr, seid, acc, N);
    edge_compute2_k<8, 64><<<(N + 15) / 16, dim3(64, 4), 0, stream>>>(acc, cnt, w12_0, cbuf + 192,
                                                                      cbuf + 192, e_b2[0], dvA, N);
    // ---- edge conv layer 1: dvA (+c1) -> dvB (64->64)
    hipMemsetAsync(acc, 0, (size_t)N * 64 * 4, stream);
    edge_scatter_delta_k<64, 6><<<(N * 64 + 255) / 256, 256, 0, stream>>>(dvA, cbuf + 0, col, acc,
                                                                          N);
    edge_compute2_k<64, 64><<<(N + 15) / 16, dim3(64, 4), 0, stream>>>(acc, cnt, w12_1, cbuf + 320,
                                                                       cbuf + 256, e_b2[1], dvB, N);
    // ---- edge conv layer 2: dvB (+c2) -> dvA (64->32)
    hipMemsetAsync(acc, 0, (size_t)N * 64 * 4, stream);
    edge_scatter_delta_k<64, 6><<<(N * 64 + 255) / 256, 256, 0, stream>>>(dvB, cbuf + 64, col, acc,
                                                                          N);
    edge_compute2_k<64, 32><<<(N + 31) / 32, dim3(32, 8), 0, stream>>>(acc, cnt, w12_2, cbuf + 416,
                                                                       cbuf + 384, e_b2[2], dvA, N);
    // ---- edge conv layer 3: dvA (+c3) -> dvB (32->32)
    hipMemsetAsync(acc, 0, (size_t)N * 32 * 4, stream);
    edge_scatter_delta_k<32, 5><<<(N * 32 + 255) / 256, 256, 0, stream>>>(dvA, cbuf + 128, col, acc,
                                                                          N);
    edge_compute2_k<32, 32><<<(N + 31) / 32, dim3(32, 8), 0, stream>>>(acc, cnt, w12_3, cbuf + 480,
                                                                       cbuf + 448, e_b2[3], dvB, N);

    // ---- final per-edge output
    final_k<<<(E + 255) / 256, 256, 0, stream>>>(hB, dvB, cbuf + 160, row, col, fcw, fcb,
                                                 (float*)d_out, E, N);
}